// Round 1
// 402.236 us; speedup vs baseline: 1.2288x; 1.2288x over previous
//
#include <hip/hip_runtime.h>
#include <hip/hip_bf16.h>

// B=4, S=2048, D=1024, H=16, DK=DV=64. Inputs f32, output f32 (confirmed r8).
// MFMA math bf16 with f32 accum. Round 10: flash_kernel rewritten with
// swapped-operand QK^T (S^T): softmax row is lane-local (q=l16), so the
// reductions are in-lane + 2 shuffles, P-store is vectorized b64, and the
// next K/V tile is prefetched into registers during compute (T14).

typedef __attribute__((ext_vector_type(8))) short bf16x8;
typedef __attribute__((ext_vector_type(4))) float f32x4;
typedef __attribute__((ext_vector_type(4))) unsigned int u32x4;
typedef __attribute__((ext_vector_type(2))) unsigned int u32x2;

#define MFMA16(a, b, c) __builtin_amdgcn_mfma_f32_16x16x32_bf16((a), (b), (c), 0, 0, 0)

#define LOG2E 1.44269504088896340736f
#define BIG_NEG (-3.0e38f)

__device__ __forceinline__ unsigned short f2bf(float f) {
  union { float f; unsigned int i; } x; x.f = f;
  unsigned int lsb = (x.i >> 16) & 1;
  x.i += 0x7fffu + lsb;  // RNE (finite inputs only)
  return (unsigned short)(x.i >> 16);
}

// ---------------------------------------------------------------------------
// Batched transpose + downconvert: in f32 [batch][R][C] -> out bf16 [batch][C][R]
// ---------------------------------------------------------------------------
__global__ void wtrans_kernel(const float* __restrict__ in,
                              unsigned short* __restrict__ out, int R, int C) {
  __shared__ unsigned short tile[32][33];
  const int bz = blockIdx.z;
  const int c0 = blockIdx.x * 32, r0 = blockIdx.y * 32;
  const float* ip = in + (size_t)bz * R * C;
  unsigned short* op = out + (size_t)bz * R * C;
  const int tx = threadIdx.x, ty = threadIdx.y;  // (32, 8)
#pragma unroll
  for (int i = 0; i < 32; i += 8)
    tile[ty + i][tx] = f2bf(ip[(size_t)(r0 + ty + i) * C + (c0 + tx)]);
  __syncthreads();
#pragma unroll
  for (int i = 0; i < 32; i += 8)
    op[(size_t)(c0 + ty + i) * R + (r0 + tx)] = tile[tx][ty + i];
}

// ---------------------------------------------------------------------------
// QKV projection, GROUP of nb batches: embG f32 [nb*2048][1024] x WtT bf16
// [h][c][d] -> Q,K bf16 [(b*16+h)][s][64], V transposed -> Vt [(b*16+h)][dv][s].
// Grid (8, 16*nb, 3). Tile 128x128, BK=32, 4 waves, 4x4 accs/wave.
// ---------------------------------------------------------------------------
__global__ __launch_bounds__(256)
void qkv_kernel(const float* __restrict__ embG,
                const unsigned short* __restrict__ WqT,
                const unsigned short* __restrict__ WkT,
                const unsigned short* __restrict__ WvT,
                unsigned short* __restrict__ QG,
                unsigned short* __restrict__ KG,
                unsigned short* __restrict__ VtG) {
  const int t = blockIdx.z;           // 0=Q, 1=K, 2=V
  const int m0 = blockIdx.y * 128;    // row in [0, nb*2048)
  const int n0 = blockIdx.x * 128;    // col in [0, 1024)
  const int b = m0 >> 11;             // local batch (tile never crosses: 2048%128==0)
  const int sloc = m0 & 2047;
  const unsigned short* Wt =
      (t == 0 ? WqT : (t == 1 ? WkT : WvT)) + (size_t)(n0 >> 6) * 64 * 1024;

  __shared__ __align__(16) unsigned short As[128][40];  // [m][k], +8 pad
  __shared__ __align__(16) unsigned short Bs[128][40];  // [n][k]

  const int tid = threadIdx.x;
  const int lane = tid & 63, w = tid >> 6;
  const int q4 = lane >> 4, l16 = lane & 15;
  const int arow = tid >> 1, acol = (tid & 1) * 16;

  f32x4 acc[4][4] = {};

  for (int k0 = 0; k0 < 1024; k0 += 32) {
    __syncthreads();
    {
      const float* erow = &embG[(size_t)(m0 + arow) * 1024 + k0 + acol];
      const float4 v0 = *(const float4*)&erow[0];
      const float4 v1 = *(const float4*)&erow[4];
      const float4 v2 = *(const float4*)&erow[8];
      const float4 v3 = *(const float4*)&erow[12];
      union { unsigned short u[8]; u32x4 v; } p0, p1;
      p0.u[0] = f2bf(v0.x); p0.u[1] = f2bf(v0.y); p0.u[2] = f2bf(v0.z); p0.u[3] = f2bf(v0.w);
      p0.u[4] = f2bf(v1.x); p0.u[5] = f2bf(v1.y); p0.u[6] = f2bf(v1.z); p0.u[7] = f2bf(v1.w);
      p1.u[0] = f2bf(v2.x); p1.u[1] = f2bf(v2.y); p1.u[2] = f2bf(v2.z); p1.u[3] = f2bf(v2.w);
      p1.u[4] = f2bf(v3.x); p1.u[5] = f2bf(v3.y); p1.u[6] = f2bf(v3.z); p1.u[7] = f2bf(v3.w);
      *(u32x4*)&As[arow][acol]     = p0.v;
      *(u32x4*)&As[arow][acol + 8] = p1.v;
    }
    *(u32x4*)&Bs[arow][acol]     = *(const u32x4*)&Wt[(size_t)arow * 1024 + k0 + acol];
    *(u32x4*)&Bs[arow][acol + 8] = *(const u32x4*)&Wt[(size_t)arow * 1024 + k0 + acol + 8];
    __syncthreads();

    // t==2: compute (W^T * emb^T) = V^T directly by swapping operand roles.
    const unsigned short (*PA)[40] = (t == 2) ? Bs : As;
    const unsigned short (*PB)[40] = (t == 2) ? As : Bs;

    bf16x8 af[4], bfr[4];
#pragma unroll
    for (int ms = 0; ms < 4; ++ms)
      af[ms] = *(const bf16x8*)&PA[(w >> 1) * 64 + ms * 16 + l16][q4 * 8];
#pragma unroll
    for (int js = 0; js < 4; ++js)
      bfr[js] = *(const bf16x8*)&PB[(w & 1) * 64 + js * 16 + l16][q4 * 8];
#pragma unroll
    for (int ms = 0; ms < 4; ++ms)
#pragma unroll
      for (int js = 0; js < 4; ++js)
        acc[ms][js] = MFMA16(af[ms], bfr[js], acc[ms][js]);
  }

  if (t < 2) {
    unsigned short* outp = (t == 0) ? QG : KG;
    const int h = (n0 >> 6) + (w & 1);
    const size_t hb = (size_t)(b * 16 + h) * 2048;
#pragma unroll
    for (int ms = 0; ms < 4; ++ms)
#pragma unroll
      for (int js = 0; js < 4; ++js) {
        const int c = js * 16 + l16;
#pragma unroll
        for (int r = 0; r < 4; ++r) {
          const int s = sloc + (w >> 1) * 64 + ms * 16 + q4 * 4 + r;
          outp[(hb + s) * 64 + c] = f2bf(acc[ms][js][r]);
        }
      }
  } else {
    const int h = (n0 >> 6) + (w >> 1);
    const size_t hb = (size_t)(b * 16 + h) * 64;
#pragma unroll
    for (int ms = 0; ms < 4; ++ms)
#pragma unroll
      for (int js = 0; js < 4; ++js) {
        const int s = sloc + (w & 1) * 64 + js * 16 + l16;
#pragma unroll
        for (int r = 0; r < 4; ++r) {
          const int c = ms * 16 + q4 * 4 + r;
          VtG[(hb + c) * 2048 + s] = f2bf(acc[ms][js][r]);
        }
      }
  }
}

// ---------------------------------------------------------------------------
// Flash attention, causal, GROUP of nb batches. Grid (32, 16*nb);
// blockIdx.y = local bh = b*16+h. Each wave owns 16 q-rows.
// Swapped-operand scheme: S^T = mfma(K,Q) so each lane's column is one q-row
// (q = l16); row stats are in-lane + 2 shuffles; P-store is 4x ds_write_b64;
// PV computed as O^T = mfma(V^T, P^T). Next K/V tile prefetched into regs
// during compute (async-STAGE split, T14).
// ---------------------------------------------------------------------------
__global__ __launch_bounds__(256)
void flash_kernel(const unsigned short* __restrict__ QG,
                  const unsigned short* __restrict__ KG,
                  const unsigned short* __restrict__ VtG,
                  unsigned short* __restrict__ ObG) {
  const int bh = blockIdx.y;
  const int qt = (gridDim.x - 1) - blockIdx.x;  // longest blocks dispatch first
  const int q0 = qt * 64;
  const int tid = threadIdx.x;
  const int lane = tid & 63, w = tid >> 6;
  const int q4 = lane >> 4, l16 = lane & 15;

  const unsigned short* Qp = QG + ((size_t)bh * 2048 + q0 + w * 16) * 64;
  const unsigned short* Kp = KG + (size_t)bh * 2048 * 64;
  const unsigned short* Vp = VtG + (size_t)bh * 64 * 2048;

  // B-fragment of Q for S^T mfma: lane holds Q[q=l16][d=q4*8..+8]
  const bf16x8 qf0 = *(const bf16x8*)&Qp[(size_t)l16 * 64 + q4 * 8];
  const bf16x8 qf1 = *(const bf16x8*)&Qp[(size_t)l16 * 64 + 32 + q4 * 8];

  __shared__ __align__(16) unsigned short Ks[64][72];        // [s][d]
  __shared__ __align__(16) unsigned short Vs[64][72];        // [dv][s]
  __shared__ __align__(16) unsigned short Plds[4][16][72];   // per-wave P[q][k]

  f32x4 oacc[4] = {};        // O^T: oacc[js][r] = O[q=l16][dv=js*16+q4*4+r]
  float m_i = BIG_NEG, l_i = 0.f;

  const float sscale = 0.125f * LOG2E;  // softmax in exp2 domain

  // prologue: load tile j0=0 into registers
  const int sr = tid >> 3, sc = (tid & 7) * 8;
  u32x4 kreg0 = *(const u32x4*)&Kp[(size_t)sr * 64 + sc];
  u32x4 kreg1 = *(const u32x4*)&Kp[(size_t)(sr + 32) * 64 + sc];
  u32x4 vreg0 = *(const u32x4*)&Vp[(size_t)sr * 2048 + sc];
  u32x4 vreg1 = *(const u32x4*)&Vp[(size_t)(sr + 32) * 2048 + sc];

  for (int j0 = 0; j0 <= q0; j0 += 64) {
    // write staged regs to LDS (vmcnt wait here is hidden behind prev compute)
    *(u32x4*)&Ks[sr][sc]      = kreg0;
    *(u32x4*)&Ks[sr + 32][sc] = kreg1;
    *(u32x4*)&Vs[sr][sc]      = vreg0;
    *(u32x4*)&Vs[sr + 32][sc] = vreg1;
    __syncthreads();

    // prefetch next tile into regs; overlaps with the compute below
    if (j0 + 64 <= q0) {
      const int jn = j0 + 64;
      kreg0 = *(const u32x4*)&Kp[(size_t)(jn + sr) * 64 + sc];
      kreg1 = *(const u32x4*)&Kp[(size_t)(jn + sr + 32) * 64 + sc];
      vreg0 = *(const u32x4*)&Vp[(size_t)sr * 2048 + jn + sc];
      vreg1 = *(const u32x4*)&Vp[(size_t)(sr + 32) * 2048 + jn + sc];
    }

    // S^T tile: sacc[js][r] = S[q=l16][k = js*16 + q4*4 + r]
    f32x4 sacc[4] = {};
#pragma unroll
    for (int js = 0; js < 4; ++js) {
      const bf16x8 kf0 = *(const bf16x8*)&Ks[js * 16 + l16][q4 * 8];
      const bf16x8 kf1 = *(const bf16x8*)&Ks[js * 16 + l16][32 + q4 * 8];
      sacc[js] = MFMA16(kf0, qf0, sacc[js]);
      sacc[js] = MFMA16(kf1, qf1, sacc[js]);
    }

    // scale + causal mask + in-lane max over the 16 held k-values
    float mloc = BIG_NEG;
    if (j0 == q0) {
      const int qrel = w * 16 + l16;
#pragma unroll
      for (int js = 0; js < 4; ++js)
#pragma unroll
        for (int r = 0; r < 4; ++r) {
          const int krel = js * 16 + q4 * 4 + r;
          float v = sacc[js][r] * sscale;
          if (krel > qrel) v = BIG_NEG;
          sacc[js][r] = v;
          mloc = fmaxf(mloc, v);
        }
    } else {
#pragma unroll
      for (int js = 0; js < 4; ++js)
#pragma unroll
        for (int r = 0; r < 4; ++r) {
          const float v = sacc[js][r] * sscale;
          sacc[js][r] = v;
          mloc = fmaxf(mloc, v);
        }
    }
    // row max: reduce across the 4 q4-groups that share q=l16
    mloc = fmaxf(mloc, __shfl_xor(mloc, 16, 64));
    mloc = fmaxf(mloc, __shfl_xor(mloc, 32, 64));

    const float mnew = fmaxf(m_i, mloc);
    const float alpha = __builtin_amdgcn_exp2f(m_i - mnew);
    m_i = mnew;

    float sm = 0.f;
#pragma unroll
    for (int js = 0; js < 4; ++js)
#pragma unroll
      for (int r = 0; r < 4; ++r) {
        const float p = __builtin_amdgcn_exp2f(sacc[js][r] - mnew);
        sacc[js][r] = p;
        sm += p;
      }
    sm += __shfl_xor(sm, 16, 64);
    sm += __shfl_xor(sm, 32, 64);
    l_i = l_i * alpha + sm;

#pragma unroll
    for (int js = 0; js < 4; ++js)
#pragma unroll
      for (int r = 0; r < 4; ++r)
        oacc[js][r] *= alpha;

    // P store: row q=l16, 4 consecutive k per js -> one 8B write each
#pragma unroll
    for (int js = 0; js < 4; ++js) {
      union { unsigned short u[4]; u32x2 v; } pk;
#pragma unroll
      for (int r = 0; r < 4; ++r) pk.u[r] = f2bf(sacc[js][r]);
      *(u32x2*)&Plds[w][l16][js * 16 + q4 * 4] = pk.v;
    }

    asm volatile("" ::: "memory");

    // B-fragment of P^T: lane needs P[q=l16][k=q4*8..+8]
    const bf16x8 pf0 = *(const bf16x8*)&Plds[w][l16][q4 * 8];
    const bf16x8 pf1 = *(const bf16x8*)&Plds[w][l16][32 + q4 * 8];

#pragma unroll
    for (int js = 0; js < 4; ++js) {
      const bf16x8 vf0 = *(const bf16x8*)&Vs[js * 16 + l16][q4 * 8];
      const bf16x8 vf1 = *(const bf16x8*)&Vs[js * 16 + l16][32 + q4 * 8];
      oacc[js] = MFMA16(vf0, pf0, oacc[js]);
      oacc[js] = MFMA16(vf1, pf1, oacc[js]);
    }
    __syncthreads();  // LDS reads done before next iter's staging writes
  }

  // epilogue: concat-head layout ObG[b][s][h*64+dv]; 4 consecutive dv -> 8B store
  const int b = bh >> 4, h = bh & 15;
  const int q = q0 + w * 16 + l16;
  unsigned short* orow = ObG + ((size_t)b * 2048 + q) * 1024 + h * 64;
#pragma unroll
  for (int js = 0; js < 4; ++js) {
    union { unsigned short u[4]; u32x2 v; } ok;
#pragma unroll
    for (int r = 0; r < 4; ++r) ok.u[r] = f2bf(oacc[js][r] / l_i);
    *(u32x2*)&orow[js * 16 + q4 * 4] = ok.v;
  }
}

// ---------------------------------------------------------------------------
// Output projection, GROUP: ObG bf16 [nb*2048][1024] x WoT bf16 [n][d]
// + bo(f32) -> outG f32 [nb*2048][1024].  Grid (8, 16*nb).
// ---------------------------------------------------------------------------
__global__ __launch_bounds__(256)
void oproj_kernel(const unsigned short* __restrict__ ObG,
                  const unsigned short* __restrict__ WoT,
                  const float* __restrict__ bo,
                  float* __restrict__ outG) {
  const int m0 = blockIdx.y * 128;
  const int n0 = blockIdx.x * 128;

  __shared__ __align__(16) unsigned short As[128][40];
  __shared__ __align__(16) unsigned short Bs[128][40];

  const int tid = threadIdx.x;
  const int lane = tid & 63, w = tid >> 6;
  const int q4 = lane >> 4, l16 = lane & 15;
  const int arow = tid >> 1, acol = (tid & 1) * 16;

  f32x4 acc[4][4] = {};

  for (int k0 = 0; k0 < 1024; k0 += 32) {
    __syncthreads();
    *(u32x4*)&As[arow][acol]     = *(const u32x4*)&ObG[(size_t)(m0 + arow) * 1024 + k0 + acol];
    *(u32x4*)&As[arow][acol + 8] = *(const u32x4*)&ObG[(size_t)(m0 + arow) * 1024 + k0 + acol + 8];
    *(u32x4*)&Bs[arow][acol]     = *(const u32x4*)&WoT[(size_t)(n0 + arow) * 1024 + k0 + acol];
    *(u32x4*)&Bs[arow][acol + 8] = *(const u32x4*)&WoT[(size_t)(n0 + arow) * 1024 + k0 + acol + 8];
    __syncthreads();

    bf16x8 af[4], bfr[4];
#pragma unroll
    for (int ms = 0; ms < 4; ++ms)
      af[ms] = *(const bf16x8*)&As[(w >> 1) * 64 + ms * 16 + l16][q4 * 8];
#pragma unroll
    for (int js = 0; js < 4; ++js)
      bfr[js] = *(const bf16x8*)&Bs[(w & 1) * 64 + js * 16 + l16][q4 * 8];
#pragma unroll
    for (int ms = 0; ms < 4; ++ms)
#pragma unroll
      for (int js = 0; js < 4; ++js)
        acc[ms][js] = MFMA16(af[ms], bfr[js], acc[ms][js]);
  }

#pragma unroll
  for (int js = 0; js < 4; ++js) {
    const int col = n0 + (w & 1) * 64 + js * 16 + l16;
    const float bias = bo[col];
#pragma unroll
    for (int ms = 0; ms < 4; ++ms)
#pragma unroll
      for (int r = 0; r < 4; ++r) {
        const int row = m0 + (w >> 1) * 64 + ms * 16 + q4 * 4 + r;
        outG[(size_t)row * 1024 + col] = acc[ms][js][r] + bias;  // f32 store
      }
  }
}

// ---------------------------------------------------------------------------
extern "C" void kernel_launch(void* const* d_in, const int* in_sizes, int n_in,
                              void* d_out, int out_size, void* d_ws, size_t ws_size,
                              hipStream_t stream) {
  const float* emb = (const float*)d_in[0];   // [4][2048][1024] f32
  const float* Wq  = (const float*)d_in[1];   // [16][1024][64]  f32
  const float* Wk  = (const float*)d_in[2];
  const float* Wv  = (const float*)d_in[3];
  const float* Wo  = (const float*)d_in[4];   // [1024][1024]    f32
  const float* bo  = (const float*)d_in[5];   // [1024]          f32
  float* out = (float*)d_out;                 // [4][2048][1024] f32

  char* ws = (char*)d_ws;
  const size_t MB = 1024 * 1024;

  // group size: nb batches per pipeline pass. ws need = 8 + 16*nb MB.
  const int nb = (ws_size >= 72 * MB) ? 4 : (ws_size >= 40 * MB) ? 2 : 1;

  unsigned short* WqT = (unsigned short*)(ws + 0 * MB);              // 2 MB [h][c][d]
  unsigned short* WkT = (unsigned short*)(ws + 2 * MB);              // 2 MB
  unsigned short* WvT = (unsigned short*)(ws + 4 * MB);              // 2 MB
  unsigned short* WoT = (unsigned short*)(ws + 6 * MB);              // 2 MB [n][d]
  unsigned short* QG  = (unsigned short*)(ws + 8 * MB);              // 4*nb MB
  unsigned short* KG  = (unsigned short*)(ws + (8 + 4 * nb) * MB);   // 4*nb MB
  unsigned short* VtG = (unsigned short*)(ws + (8 + 8 * nb) * MB);   // 4*nb MB
  unsigned short* ObG = (unsigned short*)(ws + (8 + 12 * nb) * MB);  // 4*nb MB

  const dim3 tb(32, 8, 1);
  wtrans_kernel<<<dim3(2, 32, 16), tb, 0, stream>>>(Wq, WqT, 1024, 64);
  wtrans_kernel<<<dim3(2, 32, 16), tb, 0, stream>>>(Wk, WkT, 1024, 64);
  wtrans_kernel<<<dim3(2, 32, 16), tb, 0, stream>>>(Wv, WvT, 1024, 64);
  wtrans_kernel<<<dim3(32, 32, 1), tb, 0, stream>>>(Wo, WoT, 1024, 1024);

  for (int g = 0; g < 4; g += nb) {
    const float* embG = emb + (size_t)g * 2048 * 1024;
    float* outG = out + (size_t)g * 2048 * 1024;
    qkv_kernel<<<dim3(8, 16 * nb, 3), 256, 0, stream>>>(embG, WqT, WkT, WvT, QG, KG, VtG);
    flash_kernel<<<dim3(32, 16 * nb), 256, 0, stream>>>(QG, KG, VtG, ObG);
    oproj_kernel<<<dim3(8, 16 * nb), 256, 0, stream>>>(ObG, WoT, bo, outG);
  }
}

// Round 2
// 304.295 us; speedup vs baseline: 1.6243x; 1.3219x over previous
//
#include <hip/hip_runtime.h>
#include <hip/hip_bf16.h>

// B=4, S=2048, D=1024, H=16, DK=DV=64. Inputs f32, output f32 (confirmed r8).
// MFMA math bf16 with f32 accum. Round 11:
//  - flash: balanced causal pairing (block = q-tiles x and 31-x, 8 waves/512thr,
//    uniform 33 compute-tiles/block, exactly 4 blocks/CU resident -> no tail),
//    defer-max (T13), v_cvt_pk_bf16_f32 P-store, Q pre-scaled by 0.125*log2e.
//  - qkv: emb pre-converted to bf16 once per group (embconv into the ObG
//    region, which is dead until flash writes it) -> staging is pure copies.

typedef __attribute__((ext_vector_type(8))) short bf16x8;
typedef __attribute__((ext_vector_type(4))) float f32x4;
typedef __attribute__((ext_vector_type(4))) unsigned int u32x4;
typedef __attribute__((ext_vector_type(2))) unsigned int u32x2;

#define MFMA16(a, b, c) __builtin_amdgcn_mfma_f32_16x16x32_bf16((a), (b), (c), 0, 0, 0)

#define LOG2E 1.44269504088896340736f
#define BIG_NEG (-3.0e38f)
#define DEFER_THR 10.0f  // log2-domain; P bounded by 2^10 when rescale skipped

__device__ __forceinline__ unsigned short f2bf(float f) {
  union { float f; unsigned int i; } x; x.f = f;
  unsigned int lsb = (x.i >> 16) & 1;
  x.i += 0x7fffu + lsb;  // RNE (finite inputs only)
  return (unsigned short)(x.i >> 16);
}

__device__ __forceinline__ unsigned int cvtpk(float lo, float hi) {
  unsigned int r;
  asm("v_cvt_pk_bf16_f32 %0, %1, %2" : "=v"(r) : "v"(lo), "v"(hi));
  return r;
}

// ---------------------------------------------------------------------------
// Batched transpose + downconvert: in f32 [batch][R][C] -> out bf16 [batch][C][R]
// ---------------------------------------------------------------------------
__global__ void wtrans_kernel(const float* __restrict__ in,
                              unsigned short* __restrict__ out, int R, int C) {
  __shared__ unsigned short tile[32][33];
  const int bz = blockIdx.z;
  const int c0 = blockIdx.x * 32, r0 = blockIdx.y * 32;
  const float* ip = in + (size_t)bz * R * C;
  unsigned short* op = out + (size_t)bz * R * C;
  const int tx = threadIdx.x, ty = threadIdx.y;  // (32, 8)
#pragma unroll
  for (int i = 0; i < 32; i += 8)
    tile[ty + i][tx] = f2bf(ip[(size_t)(r0 + ty + i) * C + (c0 + tx)]);
  __syncthreads();
#pragma unroll
  for (int i = 0; i < 32; i += 8)
    op[(size_t)(c0 + ty + i) * R + (r0 + tx)] = tile[tx][ty + i];
}

// ---------------------------------------------------------------------------
// f32 -> bf16 bulk convert (emb). Grid covers exactly n/8 threads.
// ---------------------------------------------------------------------------
__global__ __launch_bounds__(256)
void embconv_kernel(const float* __restrict__ in, unsigned short* __restrict__ out) {
  const int i = blockIdx.x * 256 + threadIdx.x;
  const float4 a = ((const float4*)in)[2 * i];
  const float4 b = ((const float4*)in)[2 * i + 1];
  union { unsigned short u[8]; u32x4 v; } p;
  p.u[0] = f2bf(a.x); p.u[1] = f2bf(a.y); p.u[2] = f2bf(a.z); p.u[3] = f2bf(a.w);
  p.u[4] = f2bf(b.x); p.u[5] = f2bf(b.y); p.u[6] = f2bf(b.z); p.u[7] = f2bf(b.w);
  ((u32x4*)out)[i] = p.v;
}

// ---------------------------------------------------------------------------
// QKV projection, GROUP of nb batches: embB bf16 [nb*2048][1024] x WtT bf16
// [h][c][d] -> Q (pre-scaled by 0.125*log2e), K bf16 [(b*16+h)][s][64],
// V transposed -> Vt [(b*16+h)][dv][s]. Grid (8, 16*nb, 3).
// ---------------------------------------------------------------------------
__global__ __launch_bounds__(256)
void qkv_kernel(const unsigned short* __restrict__ embB,
                const unsigned short* __restrict__ WqT,
                const unsigned short* __restrict__ WkT,
                const unsigned short* __restrict__ WvT,
                unsigned short* __restrict__ QG,
                unsigned short* __restrict__ KG,
                unsigned short* __restrict__ VtG) {
  const int t = blockIdx.z;           // 0=Q, 1=K, 2=V
  const int m0 = blockIdx.y * 128;    // row in [0, nb*2048)
  const int n0 = blockIdx.x * 128;    // col in [0, 1024)
  const int b = m0 >> 11;             // local batch (tile never crosses)
  const int sloc = m0 & 2047;
  const unsigned short* Wt =
      (t == 0 ? WqT : (t == 1 ? WkT : WvT)) + (size_t)(n0 >> 6) * 64 * 1024;

  __shared__ __align__(16) unsigned short As[128][40];  // [m][k], +8 pad
  __shared__ __align__(16) unsigned short Bs[128][40];  // [n][k]

  const int tid = threadIdx.x;
  const int lane = tid & 63, w = tid >> 6;
  const int q4 = lane >> 4, l16 = lane & 15;
  const int arow = tid >> 1, acol = (tid & 1) * 16;

  f32x4 acc[4][4] = {};

  for (int k0 = 0; k0 < 1024; k0 += 32) {
    __syncthreads();
    *(u32x4*)&As[arow][acol]     = *(const u32x4*)&embB[(size_t)(m0 + arow) * 1024 + k0 + acol];
    *(u32x4*)&As[arow][acol + 8] = *(const u32x4*)&embB[(size_t)(m0 + arow) * 1024 + k0 + acol + 8];
    *(u32x4*)&Bs[arow][acol]     = *(const u32x4*)&Wt[(size_t)arow * 1024 + k0 + acol];
    *(u32x4*)&Bs[arow][acol + 8] = *(const u32x4*)&Wt[(size_t)arow * 1024 + k0 + acol + 8];
    __syncthreads();

    // t==2: compute (W^T * emb^T) = V^T directly by swapping operand roles.
    const unsigned short (*PA)[40] = (t == 2) ? Bs : As;
    const unsigned short (*PB)[40] = (t == 2) ? As : Bs;

    bf16x8 af[4], bfr[4];
#pragma unroll
    for (int ms = 0; ms < 4; ++ms)
      af[ms] = *(const bf16x8*)&PA[(w >> 1) * 64 + ms * 16 + l16][q4 * 8];
#pragma unroll
    for (int js = 0; js < 4; ++js)
      bfr[js] = *(const bf16x8*)&PB[(w & 1) * 64 + js * 16 + l16][q4 * 8];
#pragma unroll
    for (int ms = 0; ms < 4; ++ms)
#pragma unroll
      for (int js = 0; js < 4; ++js)
        acc[ms][js] = MFMA16(af[ms], bfr[js], acc[ms][js]);
  }

  if (t < 2) {
    unsigned short* outp = (t == 0) ? QG : KG;
    const float osc = (t == 0) ? (0.125f * LOG2E) : 1.0f;  // fold softmax scale into Q
    const int h = (n0 >> 6) + (w & 1);
    const size_t hb = (size_t)(b * 16 + h) * 2048;
#pragma unroll
    for (int ms = 0; ms < 4; ++ms)
#pragma unroll
      for (int js = 0; js < 4; ++js) {
        const int c = js * 16 + l16;
#pragma unroll
        for (int r = 0; r < 4; ++r) {
          const int s = sloc + (w >> 1) * 64 + ms * 16 + q4 * 4 + r;
          outp[(hb + s) * 64 + c] = f2bf(acc[ms][js][r] * osc);
        }
      }
  } else {
    const int h = (n0 >> 6) + (w >> 1);
    const size_t hb = (size_t)(b * 16 + h) * 64;
#pragma unroll
    for (int ms = 0; ms < 4; ++ms)
#pragma unroll
      for (int js = 0; js < 4; ++js) {
        const int s = sloc + (w & 1) * 64 + js * 16 + l16;
#pragma unroll
        for (int r = 0; r < 4; ++r) {
          const int c = ms * 16 + q4 * 4 + r;
          VtG[(hb + c) * 2048 + s] = f2bf(acc[ms][js][r]);
        }
      }
  }
}

// ---------------------------------------------------------------------------
// Flash attention, causal, balanced pairing. Grid (16, 16*nb), 512 threads.
// Block x handles q-tiles (31-x) [waves 0-3] and (x) [waves 4-7]: every block
// does exactly 33 wave-tile units. K/V staged once, shared by all 8 waves.
// Swapped-operand S^T = mfma(K,Q): softmax row is lane-local (q=l16).
// ---------------------------------------------------------------------------
__global__ __launch_bounds__(512)
void flash_kernel(const unsigned short* __restrict__ QG,
                  const unsigned short* __restrict__ KG,
                  const unsigned short* __restrict__ VtG,
                  unsigned short* __restrict__ ObG) {
  const int bh = blockIdx.y;
  const int x = blockIdx.x;                 // 0..15
  const int q0B = (31 - x) * 64;            // long phase (waves 0-3)
  const int tid = threadIdx.x;
  const int lane = tid & 63, w = tid >> 6;  // w in 0..7
  const int wp = w & 3;
  const int q0w = (w < 4) ? q0B : x * 64;   // this wave's q-tile base
  const int q4 = lane >> 4, l16 = lane & 15;

  const unsigned short* Qp = QG + ((size_t)bh * 2048 + q0w + wp * 16) * 64;
  const unsigned short* Kp = KG + (size_t)bh * 2048 * 64;
  const unsigned short* Vp = VtG + (size_t)bh * 64 * 2048;

  // B-fragment of Q for S^T mfma: lane holds Q[q=l16][d=q4*8..+8] (pre-scaled)
  const bf16x8 qf0 = *(const bf16x8*)&Qp[(size_t)l16 * 64 + q4 * 8];
  const bf16x8 qf1 = *(const bf16x8*)&Qp[(size_t)l16 * 64 + 32 + q4 * 8];

  __shared__ __align__(16) unsigned short Ks[64][72];       // [s][d]
  __shared__ __align__(16) unsigned short Vs[64][72];       // [dv][s]
  __shared__ __align__(16) unsigned short Plds[8][16][72];  // per-wave P[q][k]

  f32x4 oacc[4] = {};  // O^T: oacc[js][r] = O[q=l16][dv=js*16+q4*4+r]
  float m_i = BIG_NEG, l_i = 0.f;

  // staging: 512 threads, one 16B K-slice + one 16B V-slice each
  const int sr = tid >> 3, sc = (tid & 7) * 8;
  u32x4 kreg = *(const u32x4*)&Kp[(size_t)sr * 64 + sc];
  u32x4 vreg = *(const u32x4*)&Vp[(size_t)sr * 2048 + sc];

  for (int j0 = 0; j0 <= q0B; j0 += 64) {
    *(u32x4*)&Ks[sr][sc] = kreg;
    *(u32x4*)&Vs[sr][sc] = vreg;
    __syncthreads();

    // prefetch next tile into regs; overlaps with the compute below (T14)
    if (j0 + 64 <= q0B) {
      const int jn = j0 + 64;
      kreg = *(const u32x4*)&Kp[(size_t)(jn + sr) * 64 + sc];
      vreg = *(const u32x4*)&Vp[(size_t)sr * 2048 + jn + sc];
    }

    if (j0 <= q0w) {  // wave-uniform: this wave's q-tile still has work
      // S^T tile: sacc[js][r] = S[q=l16][k = js*16 + q4*4 + r] (log2 domain)
      f32x4 sacc[4] = {};
#pragma unroll
      for (int js = 0; js < 4; ++js) {
        const bf16x8 kf0 = *(const bf16x8*)&Ks[js * 16 + l16][q4 * 8];
        const bf16x8 kf1 = *(const bf16x8*)&Ks[js * 16 + l16][32 + q4 * 8];
        sacc[js] = MFMA16(kf0, qf0, sacc[js]);
        sacc[js] = MFMA16(kf1, qf1, sacc[js]);
      }

      // causal mask (diag tile only) + in-lane max
      float mloc = BIG_NEG;
      if (j0 == q0w) {
        const int qrel = wp * 16 + l16;
#pragma unroll
        for (int js = 0; js < 4; ++js)
#pragma unroll
          for (int r = 0; r < 4; ++r) {
            const int krel = js * 16 + q4 * 4 + r;
            float v = sacc[js][r];
            if (krel > qrel) v = BIG_NEG;
            sacc[js][r] = v;
            mloc = fmaxf(mloc, v);
          }
      } else {
#pragma unroll
        for (int js = 0; js < 4; ++js)
#pragma unroll
          for (int r = 0; r < 4; ++r) mloc = fmaxf(mloc, sacc[js][r]);
      }
      // row max across the 4 q4-groups sharing q=l16
      mloc = fmaxf(mloc, __shfl_xor(mloc, 16, 64));
      mloc = fmaxf(mloc, __shfl_xor(mloc, 32, 64));

      // defer-max (T13): only rescale when the running max grew past THR
      if (__any(mloc > m_i + DEFER_THR)) {
        const float mnew = fmaxf(m_i, mloc);
        const float alpha = __builtin_amdgcn_exp2f(m_i - mnew);
        m_i = mnew;
        l_i *= alpha;
#pragma unroll
        for (int js = 0; js < 4; ++js)
#pragma unroll
          for (int r = 0; r < 4; ++r) oacc[js][r] *= alpha;
      }

      float sm = 0.f;
#pragma unroll
      for (int js = 0; js < 4; ++js)
#pragma unroll
        for (int r = 0; r < 4; ++r) {
          const float p = __builtin_amdgcn_exp2f(sacc[js][r] - m_i);
          sacc[js][r] = p;
          sm += p;
        }
      sm += __shfl_xor(sm, 16, 64);
      sm += __shfl_xor(sm, 32, 64);
      l_i += sm;

      // P store: row q=l16, 4 consecutive k per js -> one 8B write each
#pragma unroll
      for (int js = 0; js < 4; ++js) {
        u32x2 pk;
        pk[0] = cvtpk(sacc[js][0], sacc[js][1]);
        pk[1] = cvtpk(sacc[js][2], sacc[js][3]);
        *(u32x2*)&Plds[w][l16][js * 16 + q4 * 4] = pk;
      }

      asm volatile("" ::: "memory");

      // B-fragment of P^T: lane needs P[q=l16][k=q4*8..+8]
      const bf16x8 pf0 = *(const bf16x8*)&Plds[w][l16][q4 * 8];
      const bf16x8 pf1 = *(const bf16x8*)&Plds[w][l16][32 + q4 * 8];

#pragma unroll
      for (int js = 0; js < 4; ++js) {
        const bf16x8 vf0 = *(const bf16x8*)&Vs[js * 16 + l16][q4 * 8];
        const bf16x8 vf1 = *(const bf16x8*)&Vs[js * 16 + l16][32 + q4 * 8];
        oacc[js] = MFMA16(vf0, pf0, oacc[js]);
        oacc[js] = MFMA16(vf1, pf1, oacc[js]);
      }
    }
    __syncthreads();  // all LDS reads done before next iter's staging writes
  }

  // epilogue: concat-head layout ObG[b][s][h*64+dv]; 4 consecutive dv per 8B
  const int b = bh >> 4, h = bh & 15;
  const int q = q0w + wp * 16 + l16;
  const float rl = 1.0f / l_i;
  unsigned short* orow = ObG + ((size_t)b * 2048 + q) * 1024 + h * 64;
#pragma unroll
  for (int js = 0; js < 4; ++js) {
    u32x2 ok;
    ok[0] = cvtpk(oacc[js][0] * rl, oacc[js][1] * rl);
    ok[1] = cvtpk(oacc[js][2] * rl, oacc[js][3] * rl);
    *(u32x2*)&orow[js * 16 + q4 * 4] = ok;
  }
}

// ---------------------------------------------------------------------------
// Output projection, GROUP: ObG bf16 [nb*2048][1024] x WoT bf16 [n][d]
// + bo(f32) -> outG f32 [nb*2048][1024].  Grid (8, 16*nb).
// ---------------------------------------------------------------------------
__global__ __launch_bounds__(256)
void oproj_kernel(const unsigned short* __restrict__ ObG,
                  const unsigned short* __restrict__ WoT,
                  const float* __restrict__ bo,
                  float* __restrict__ outG) {
  const int m0 = blockIdx.y * 128;
  const int n0 = blockIdx.x * 128;

  __shared__ __align__(16) unsigned short As[128][40];
  __shared__ __align__(16) unsigned short Bs[128][40];

  const int tid = threadIdx.x;
  const int lane = tid & 63, w = tid >> 6;
  const int q4 = lane >> 4, l16 = lane & 15;
  const int arow = tid >> 1, acol = (tid & 1) * 16;

  f32x4 acc[4][4] = {};

  for (int k0 = 0; k0 < 1024; k0 += 32) {
    __syncthreads();
    *(u32x4*)&As[arow][acol]     = *(const u32x4*)&ObG[(size_t)(m0 + arow) * 1024 + k0 + acol];
    *(u32x4*)&As[arow][acol + 8] = *(const u32x4*)&ObG[(size_t)(m0 + arow) * 1024 + k0 + acol + 8];
    *(u32x4*)&Bs[arow][acol]     = *(const u32x4*)&WoT[(size_t)(n0 + arow) * 1024 + k0 + acol];
    *(u32x4*)&Bs[arow][acol + 8] = *(const u32x4*)&WoT[(size_t)(n0 + arow) * 1024 + k0 + acol + 8];
    __syncthreads();

    bf16x8 af[4], bfr[4];
#pragma unroll
    for (int ms = 0; ms < 4; ++ms)
      af[ms] = *(const bf16x8*)&As[(w >> 1) * 64 + ms * 16 + l16][q4 * 8];
#pragma unroll
    for (int js = 0; js < 4; ++js)
      bfr[js] = *(const bf16x8*)&Bs[(w & 1) * 64 + js * 16 + l16][q4 * 8];
#pragma unroll
    for (int ms = 0; ms < 4; ++ms)
#pragma unroll
      for (int js = 0; js < 4; ++js)
        acc[ms][js] = MFMA16(af[ms], bfr[js], acc[ms][js]);
  }

#pragma unroll
  for (int js = 0; js < 4; ++js) {
    const int col = n0 + (w & 1) * 64 + js * 16 + l16;
    const float bias = bo[col];
#pragma unroll
    for (int ms = 0; ms < 4; ++ms)
#pragma unroll
      for (int r = 0; r < 4; ++r) {
        const int row = m0 + (w >> 1) * 64 + ms * 16 + q4 * 4 + r;
        outG[(size_t)row * 1024 + col] = acc[ms][js][r] + bias;  // f32 store
      }
  }
}

// ---------------------------------------------------------------------------
extern "C" void kernel_launch(void* const* d_in, const int* in_sizes, int n_in,
                              void* d_out, int out_size, void* d_ws, size_t ws_size,
                              hipStream_t stream) {
  const float* emb = (const float*)d_in[0];   // [4][2048][1024] f32
  const float* Wq  = (const float*)d_in[1];   // [16][1024][64]  f32
  const float* Wk  = (const float*)d_in[2];
  const float* Wv  = (const float*)d_in[3];
  const float* Wo  = (const float*)d_in[4];   // [1024][1024]    f32
  const float* bo  = (const float*)d_in[5];   // [1024]          f32
  float* out = (float*)d_out;                 // [4][2048][1024] f32

  char* ws = (char*)d_ws;
  const size_t MB = 1024 * 1024;

  // group size: nb batches per pipeline pass. ws need = 8 + 16*nb MB.
  const int nb = (ws_size >= 72 * MB) ? 4 : (ws_size >= 40 * MB) ? 2 : 1;

  unsigned short* WqT = (unsigned short*)(ws + 0 * MB);              // 2 MB [h][c][d]
  unsigned short* WkT = (unsigned short*)(ws + 2 * MB);              // 2 MB
  unsigned short* WvT = (unsigned short*)(ws + 4 * MB);              // 2 MB
  unsigned short* WoT = (unsigned short*)(ws + 6 * MB);              // 2 MB [n][d]
  unsigned short* QG  = (unsigned short*)(ws + 8 * MB);              // 4*nb MB
  unsigned short* KG  = (unsigned short*)(ws + (8 + 4 * nb) * MB);   // 4*nb MB
  unsigned short* VtG = (unsigned short*)(ws + (8 + 8 * nb) * MB);   // 4*nb MB
  unsigned short* ObG = (unsigned short*)(ws + (8 + 12 * nb) * MB);  // 4*nb MB

  const dim3 tb(32, 8, 1);
  wtrans_kernel<<<dim3(2, 32, 16), tb, 0, stream>>>(Wq, WqT, 1024, 64);
  wtrans_kernel<<<dim3(2, 32, 16), tb, 0, stream>>>(Wk, WkT, 1024, 64);
  wtrans_kernel<<<dim3(2, 32, 16), tb, 0, stream>>>(Wv, WvT, 1024, 64);
  wtrans_kernel<<<dim3(32, 32, 1), tb, 0, stream>>>(Wo, WoT, 1024, 1024);

  for (int g = 0; g < 4; g += nb) {
    const float* embG = emb + (size_t)g * 2048 * 1024;
    float* outG = out + (size_t)g * 2048 * 1024;
    // embB (bf16 emb) aliases ObG: dead before flash writes ObG, per group.
    unsigned short* embB = ObG;
    embconv_kernel<<<dim3(nb * 1024), 256, 0, stream>>>(embG, embB);
    qkv_kernel<<<dim3(8, 16 * nb, 3), 256, 0, stream>>>(embB, WqT, WkT, WvT, QG, KG, VtG);
    flash_kernel<<<dim3(16, 16 * nb), 512, 0, stream>>>(QG, KG, VtG, ObG);
    oproj_kernel<<<dim3(8, 16 * nb), 256, 0, stream>>>(ObG, WoT, bo, outG);
  }
}

// Round 3
// 291.370 us; speedup vs baseline: 1.6964x; 1.0444x over previous
//
#include <hip/hip_runtime.h>
#include <hip/hip_bf16.h>

// B=4, S=2048, D=1024, H=16, DK=DV=64. Inputs f32, output f32 (confirmed r8).
// MFMA math bf16 with f32 accum. Round 12:
//  - qkv/oproj: T14 2-phase reg-prefetch pipeline (issue next K-step's global
//    loads after the barrier; LDS-write at top of next iter) -> L2 latency
//    hides under the MFMA cluster instead of stalling every K-step.
//  - flash: grid dims swapped (bh fast, pair-index slow) so each CU's 4
//    resident blocks get a SPREAD of causal lengths (was: same length ->
//    1.9x CU imbalance). s_setprio(1) around MFMA clusters (T5).

typedef __attribute__((ext_vector_type(8))) short bf16x8;
typedef __attribute__((ext_vector_type(4))) float f32x4;
typedef __attribute__((ext_vector_type(4))) unsigned int u32x4;
typedef __attribute__((ext_vector_type(2))) unsigned int u32x2;

#define MFMA16(a, b, c) __builtin_amdgcn_mfma_f32_16x16x32_bf16((a), (b), (c), 0, 0, 0)

#define LOG2E 1.44269504088896340736f
#define BIG_NEG (-3.0e38f)
#define DEFER_THR 10.0f  // log2-domain; P bounded by 2^10 when rescale skipped

__device__ __forceinline__ unsigned short f2bf(float f) {
  union { float f; unsigned int i; } x; x.f = f;
  unsigned int lsb = (x.i >> 16) & 1;
  x.i += 0x7fffu + lsb;  // RNE (finite inputs only)
  return (unsigned short)(x.i >> 16);
}

__device__ __forceinline__ unsigned int cvtpk(float lo, float hi) {
  unsigned int r;
  asm("v_cvt_pk_bf16_f32 %0, %1, %2" : "=v"(r) : "v"(lo), "v"(hi));
  return r;
}

// ---------------------------------------------------------------------------
// Batched transpose + downconvert: in f32 [batch][R][C] -> out bf16 [batch][C][R]
// ---------------------------------------------------------------------------
__global__ void wtrans_kernel(const float* __restrict__ in,
                              unsigned short* __restrict__ out, int R, int C) {
  __shared__ unsigned short tile[32][33];
  const int bz = blockIdx.z;
  const int c0 = blockIdx.x * 32, r0 = blockIdx.y * 32;
  const float* ip = in + (size_t)bz * R * C;
  unsigned short* op = out + (size_t)bz * R * C;
  const int tx = threadIdx.x, ty = threadIdx.y;  // (32, 8)
#pragma unroll
  for (int i = 0; i < 32; i += 8)
    tile[ty + i][tx] = f2bf(ip[(size_t)(r0 + ty + i) * C + (c0 + tx)]);
  __syncthreads();
#pragma unroll
  for (int i = 0; i < 32; i += 8)
    op[(size_t)(c0 + ty + i) * R + (r0 + tx)] = tile[tx][ty + i];
}

// ---------------------------------------------------------------------------
// f32 -> bf16 bulk convert (emb). Grid covers exactly n/8 threads.
// ---------------------------------------------------------------------------
__global__ __launch_bounds__(256)
void embconv_kernel(const float* __restrict__ in, unsigned short* __restrict__ out) {
  const int i = blockIdx.x * 256 + threadIdx.x;
  const float4 a = ((const float4*)in)[2 * i];
  const float4 b = ((const float4*)in)[2 * i + 1];
  union { unsigned short u[8]; u32x4 v; } p;
  p.u[0] = f2bf(a.x); p.u[1] = f2bf(a.y); p.u[2] = f2bf(a.z); p.u[3] = f2bf(a.w);
  p.u[4] = f2bf(b.x); p.u[5] = f2bf(b.y); p.u[6] = f2bf(b.z); p.u[7] = f2bf(b.w);
  ((u32x4*)out)[i] = p.v;
}

// ---------------------------------------------------------------------------
// QKV projection, GROUP of nb batches: embB bf16 [nb*2048][1024] x WtT bf16
// [h][c][d] -> Q (pre-scaled by 0.125*log2e), K bf16 [(b*16+h)][s][64],
// V transposed -> Vt [(b*16+h)][dv][s]. Grid (8, 16*nb, 3).
// 2-phase pipeline: LDS-write staged regs, barrier, prefetch next, MFMA.
// ---------------------------------------------------------------------------
__global__ __launch_bounds__(256)
void qkv_kernel(const unsigned short* __restrict__ embB,
                const unsigned short* __restrict__ WqT,
                const unsigned short* __restrict__ WkT,
                const unsigned short* __restrict__ WvT,
                unsigned short* __restrict__ QG,
                unsigned short* __restrict__ KG,
                unsigned short* __restrict__ VtG) {
  const int t = blockIdx.z;           // 0=Q, 1=K, 2=V
  const int m0 = blockIdx.y * 128;    // row in [0, nb*2048)
  const int n0 = blockIdx.x * 128;    // col in [0, 1024)
  const int b = m0 >> 11;             // local batch (tile never crosses)
  const int sloc = m0 & 2047;
  const unsigned short* Wt =
      (t == 0 ? WqT : (t == 1 ? WkT : WvT)) + (size_t)(n0 >> 6) * 64 * 1024;

  __shared__ __align__(16) unsigned short As[128][40];  // [m][k], +8 pad
  __shared__ __align__(16) unsigned short Bs[128][40];  // [n][k]

  const int tid = threadIdx.x;
  const int lane = tid & 63, w = tid >> 6;
  const int q4 = lane >> 4, l16 = lane & 15;
  const int arow = tid >> 1, acol = (tid & 1) * 16;

  f32x4 acc[4][4] = {};

  const unsigned short* aptr = &embB[(size_t)(m0 + arow) * 1024 + acol];
  const unsigned short* bptr = &Wt[(size_t)arow * 1024 + acol];
  u32x4 a0 = *(const u32x4*)&aptr[0];
  u32x4 a1 = *(const u32x4*)&aptr[8];
  u32x4 b0 = *(const u32x4*)&bptr[0];
  u32x4 b1 = *(const u32x4*)&bptr[8];

  for (int k0 = 0; k0 < 1024; k0 += 32) {
    *(u32x4*)&As[arow][acol]     = a0;
    *(u32x4*)&As[arow][acol + 8] = a1;
    *(u32x4*)&Bs[arow][acol]     = b0;
    *(u32x4*)&Bs[arow][acol + 8] = b1;
    __syncthreads();

    if (k0 + 32 < 1024) {  // prefetch next K-step; latency hides under MFMA
      a0 = *(const u32x4*)&aptr[k0 + 32];
      a1 = *(const u32x4*)&aptr[k0 + 40];
      b0 = *(const u32x4*)&bptr[k0 + 32];
      b1 = *(const u32x4*)&bptr[k0 + 40];
    }

    // t==2: compute (W^T * emb^T) = V^T directly by swapping operand roles.
    const unsigned short (*PA)[40] = (t == 2) ? Bs : As;
    const unsigned short (*PB)[40] = (t == 2) ? As : Bs;

    bf16x8 af[4], bfr[4];
#pragma unroll
    for (int ms = 0; ms < 4; ++ms)
      af[ms] = *(const bf16x8*)&PA[(w >> 1) * 64 + ms * 16 + l16][q4 * 8];
#pragma unroll
    for (int js = 0; js < 4; ++js)
      bfr[js] = *(const bf16x8*)&PB[(w & 1) * 64 + js * 16 + l16][q4 * 8];
    __builtin_amdgcn_s_setprio(1);
#pragma unroll
    for (int ms = 0; ms < 4; ++ms)
#pragma unroll
      for (int js = 0; js < 4; ++js)
        acc[ms][js] = MFMA16(af[ms], bfr[js], acc[ms][js]);
    __builtin_amdgcn_s_setprio(0);
    __syncthreads();
  }

  if (t < 2) {
    unsigned short* outp = (t == 0) ? QG : KG;
    const float osc = (t == 0) ? (0.125f * LOG2E) : 1.0f;  // fold softmax scale into Q
    const int h = (n0 >> 6) + (w & 1);
    const size_t hb = (size_t)(b * 16 + h) * 2048;
#pragma unroll
    for (int ms = 0; ms < 4; ++ms)
#pragma unroll
      for (int js = 0; js < 4; ++js) {
        const int c = js * 16 + l16;
#pragma unroll
        for (int r = 0; r < 4; ++r) {
          const int s = sloc + (w >> 1) * 64 + ms * 16 + q4 * 4 + r;
          outp[(hb + s) * 64 + c] = f2bf(acc[ms][js][r] * osc);
        }
      }
  } else {
    const int h = (n0 >> 6) + (w >> 1);
    const size_t hb = (size_t)(b * 16 + h) * 64;
#pragma unroll
    for (int ms = 0; ms < 4; ++ms)
#pragma unroll
      for (int js = 0; js < 4; ++js) {
        const int s = sloc + (w & 1) * 64 + js * 16 + l16;
#pragma unroll
        for (int r = 0; r < 4; ++r) {
          const int c = ms * 16 + q4 * 4 + r;
          VtG[(hb + c) * 2048 + s] = f2bf(acc[ms][js][r]);
        }
      }
  }
}

// ---------------------------------------------------------------------------
// Flash attention, causal, balanced pairing. Grid (16*nb bh, 16 x), 512 thr.
// Block (bh, x) handles q-tiles (31-x) [waves 0-3] and (x) [waves 4-7].
// bh in the FAST grid dim: round-robin dispatch then gives each CU a spread
// of x values (uniform CU busy-time) instead of 4 same-length blocks.
// Swapped-operand S^T = mfma(K,Q): softmax row is lane-local (q=l16).
// ---------------------------------------------------------------------------
__global__ __launch_bounds__(512)
void flash_kernel(const unsigned short* __restrict__ QG,
                  const unsigned short* __restrict__ KG,
                  const unsigned short* __restrict__ VtG,
                  unsigned short* __restrict__ ObG) {
  const int bh = blockIdx.x;
  const int x = blockIdx.y;                 // 0..15
  const int q0B = (31 - x) * 64;            // long phase (waves 0-3)
  const int tid = threadIdx.x;
  const int lane = tid & 63, w = tid >> 6;  // w in 0..7
  const int wp = w & 3;
  const int q0w = (w < 4) ? q0B : x * 64;   // this wave's q-tile base
  const int q4 = lane >> 4, l16 = lane & 15;

  const unsigned short* Qp = QG + ((size_t)bh * 2048 + q0w + wp * 16) * 64;
  const unsigned short* Kp = KG + (size_t)bh * 2048 * 64;
  const unsigned short* Vp = VtG + (size_t)bh * 64 * 2048;

  // B-fragment of Q for S^T mfma: lane holds Q[q=l16][d=q4*8..+8] (pre-scaled)
  const bf16x8 qf0 = *(const bf16x8*)&Qp[(size_t)l16 * 64 + q4 * 8];
  const bf16x8 qf1 = *(const bf16x8*)&Qp[(size_t)l16 * 64 + 32 + q4 * 8];

  __shared__ __align__(16) unsigned short Ks[64][72];       // [s][d]
  __shared__ __align__(16) unsigned short Vs[64][72];       // [dv][s]
  __shared__ __align__(16) unsigned short Plds[8][16][72];  // per-wave P[q][k]

  f32x4 oacc[4] = {};  // O^T: oacc[js][r] = O[q=l16][dv=js*16+q4*4+r]
  float m_i = BIG_NEG, l_i = 0.f;

  // staging: 512 threads, one 16B K-slice + one 16B V-slice each
  const int sr = tid >> 3, sc = (tid & 7) * 8;
  u32x4 kreg = *(const u32x4*)&Kp[(size_t)sr * 64 + sc];
  u32x4 vreg = *(const u32x4*)&Vp[(size_t)sr * 2048 + sc];

  for (int j0 = 0; j0 <= q0B; j0 += 64) {
    *(u32x4*)&Ks[sr][sc] = kreg;
    *(u32x4*)&Vs[sr][sc] = vreg;
    __syncthreads();

    // prefetch next tile into regs; overlaps with the compute below (T14)
    if (j0 + 64 <= q0B) {
      const int jn = j0 + 64;
      kreg = *(const u32x4*)&Kp[(size_t)(jn + sr) * 64 + sc];
      vreg = *(const u32x4*)&Vp[(size_t)sr * 2048 + jn + sc];
    }

    if (j0 <= q0w) {  // wave-uniform: this wave's q-tile still has work
      // S^T tile: sacc[js][r] = S[q=l16][k = js*16 + q4*4 + r] (log2 domain)
      f32x4 sacc[4] = {};
      __builtin_amdgcn_s_setprio(1);
#pragma unroll
      for (int js = 0; js < 4; ++js) {
        const bf16x8 kf0 = *(const bf16x8*)&Ks[js * 16 + l16][q4 * 8];
        const bf16x8 kf1 = *(const bf16x8*)&Ks[js * 16 + l16][32 + q4 * 8];
        sacc[js] = MFMA16(kf0, qf0, sacc[js]);
        sacc[js] = MFMA16(kf1, qf1, sacc[js]);
      }
      __builtin_amdgcn_s_setprio(0);

      // causal mask (diag tile only) + in-lane max
      float mloc = BIG_NEG;
      if (j0 == q0w) {
        const int qrel = wp * 16 + l16;
#pragma unroll
        for (int js = 0; js < 4; ++js)
#pragma unroll
          for (int r = 0; r < 4; ++r) {
            const int krel = js * 16 + q4 * 4 + r;
            float v = sacc[js][r];
            if (krel > qrel) v = BIG_NEG;
            sacc[js][r] = v;
            mloc = fmaxf(mloc, v);
          }
      } else {
#pragma unroll
        for (int js = 0; js < 4; ++js)
#pragma unroll
          for (int r = 0; r < 4; ++r) mloc = fmaxf(mloc, sacc[js][r]);
      }
      // row max across the 4 q4-groups sharing q=l16
      mloc = fmaxf(mloc, __shfl_xor(mloc, 16, 64));
      mloc = fmaxf(mloc, __shfl_xor(mloc, 32, 64));

      // defer-max (T13): only rescale when the running max grew past THR
      if (__any(mloc > m_i + DEFER_THR)) {
        const float mnew = fmaxf(m_i, mloc);
        const float alpha = __builtin_amdgcn_exp2f(m_i - mnew);
        m_i = mnew;
        l_i *= alpha;
#pragma unroll
        for (int js = 0; js < 4; ++js)
#pragma unroll
          for (int r = 0; r < 4; ++r) oacc[js][r] *= alpha;
      }

      float sm = 0.f;
#pragma unroll
      for (int js = 0; js < 4; ++js)
#pragma unroll
        for (int r = 0; r < 4; ++r) {
          const float p = __builtin_amdgcn_exp2f(sacc[js][r] - m_i);
          sacc[js][r] = p;
          sm += p;
        }
      sm += __shfl_xor(sm, 16, 64);
      sm += __shfl_xor(sm, 32, 64);
      l_i += sm;

      // P store: row q=l16, 4 consecutive k per js -> one 8B write each
#pragma unroll
      for (int js = 0; js < 4; ++js) {
        u32x2 pk;
        pk[0] = cvtpk(sacc[js][0], sacc[js][1]);
        pk[1] = cvtpk(sacc[js][2], sacc[js][3]);
        *(u32x2*)&Plds[w][l16][js * 16 + q4 * 4] = pk;
      }

      asm volatile("" ::: "memory");

      // B-fragment of P^T: lane needs P[q=l16][k=q4*8..+8]
      const bf16x8 pf0 = *(const bf16x8*)&Plds[w][l16][q4 * 8];
      const bf16x8 pf1 = *(const bf16x8*)&Plds[w][l16][32 + q4 * 8];

      __builtin_amdgcn_s_setprio(1);
#pragma unroll
      for (int js = 0; js < 4; ++js) {
        const bf16x8 vf0 = *(const bf16x8*)&Vs[js * 16 + l16][q4 * 8];
        const bf16x8 vf1 = *(const bf16x8*)&Vs[js * 16 + l16][32 + q4 * 8];
        oacc[js] = MFMA16(vf0, pf0, oacc[js]);
        oacc[js] = MFMA16(vf1, pf1, oacc[js]);
      }
      __builtin_amdgcn_s_setprio(0);
    }
    __syncthreads();  // all LDS reads done before next iter's staging writes
  }

  // epilogue: concat-head layout ObG[b][s][h*64+dv]; 4 consecutive dv per 8B
  const int b = bh >> 4, h = bh & 15;
  const int q = q0w + wp * 16 + l16;
  const float rl = 1.0f / l_i;
  unsigned short* orow = ObG + ((size_t)b * 2048 + q) * 1024 + h * 64;
#pragma unroll
  for (int js = 0; js < 4; ++js) {
    u32x2 ok;
    ok[0] = cvtpk(oacc[js][0] * rl, oacc[js][1] * rl);
    ok[1] = cvtpk(oacc[js][2] * rl, oacc[js][3] * rl);
    *(u32x2*)&orow[js * 16 + q4 * 4] = ok;
  }
}

// ---------------------------------------------------------------------------
// Output projection, GROUP: ObG bf16 [nb*2048][1024] x WoT bf16 [n][d]
// + bo(f32) -> outG f32 [nb*2048][1024].  Grid (8, 16*nb). 2-phase pipeline.
// ---------------------------------------------------------------------------
__global__ __launch_bounds__(256)
void oproj_kernel(const unsigned short* __restrict__ ObG,
                  const unsigned short* __restrict__ WoT,
                  const float* __restrict__ bo,
                  float* __restrict__ outG) {
  const int m0 = blockIdx.y * 128;
  const int n0 = blockIdx.x * 128;

  __shared__ __align__(16) unsigned short As[128][40];
  __shared__ __align__(16) unsigned short Bs[128][40];

  const int tid = threadIdx.x;
  const int lane = tid & 63, w = tid >> 6;
  const int q4 = lane >> 4, l16 = lane & 15;
  const int arow = tid >> 1, acol = (tid & 1) * 16;

  f32x4 acc[4][4] = {};

  const unsigned short* aptr = &ObG[(size_t)(m0 + arow) * 1024 + acol];
  const unsigned short* bptr = &WoT[(size_t)(n0 + arow) * 1024 + acol];
  u32x4 a0 = *(const u32x4*)&aptr[0];
  u32x4 a1 = *(const u32x4*)&aptr[8];
  u32x4 b0 = *(const u32x4*)&bptr[0];
  u32x4 b1 = *(const u32x4*)&bptr[8];

  for (int k0 = 0; k0 < 1024; k0 += 32) {
    *(u32x4*)&As[arow][acol]     = a0;
    *(u32x4*)&As[arow][acol + 8] = a1;
    *(u32x4*)&Bs[arow][acol]     = b0;
    *(u32x4*)&Bs[arow][acol + 8] = b1;
    __syncthreads();

    if (k0 + 32 < 1024) {
      a0 = *(const u32x4*)&aptr[k0 + 32];
      a1 = *(const u32x4*)&aptr[k0 + 40];
      b0 = *(const u32x4*)&bptr[k0 + 32];
      b1 = *(const u32x4*)&bptr[k0 + 40];
    }

    bf16x8 af[4], bfr[4];
#pragma unroll
    for (int ms = 0; ms < 4; ++ms)
      af[ms] = *(const bf16x8*)&As[(w >> 1) * 64 + ms * 16 + l16][q4 * 8];
#pragma unroll
    for (int js = 0; js < 4; ++js)
      bfr[js] = *(const bf16x8*)&Bs[(w & 1) * 64 + js * 16 + l16][q4 * 8];
    __builtin_amdgcn_s_setprio(1);
#pragma unroll
    for (int ms = 0; ms < 4; ++ms)
#pragma unroll
      for (int js = 0; js < 4; ++js)
        acc[ms][js] = MFMA16(af[ms], bfr[js], acc[ms][js]);
    __builtin_amdgcn_s_setprio(0);
    __syncthreads();
  }

#pragma unroll
  for (int js = 0; js < 4; ++js) {
    const int col = n0 + (w & 1) * 64 + js * 16 + l16;
    const float bias = bo[col];
#pragma unroll
    for (int ms = 0; ms < 4; ++ms)
#pragma unroll
      for (int r = 0; r < 4; ++r) {
        const int row = m0 + (w >> 1) * 64 + ms * 16 + q4 * 4 + r;
        outG[(size_t)row * 1024 + col] = acc[ms][js][r] + bias;  // f32 store
      }
  }
}

// ---------------------------------------------------------------------------
extern "C" void kernel_launch(void* const* d_in, const int* in_sizes, int n_in,
                              void* d_out, int out_size, void* d_ws, size_t ws_size,
                              hipStream_t stream) {
  const float* emb = (const float*)d_in[0];   // [4][2048][1024] f32
  const float* Wq  = (const float*)d_in[1];   // [16][1024][64]  f32
  const float* Wk  = (const float*)d_in[2];
  const float* Wv  = (const float*)d_in[3];
  const float* Wo  = (const float*)d_in[4];   // [1024][1024]    f32
  const float* bo  = (const float*)d_in[5];   // [1024]          f32
  float* out = (float*)d_out;                 // [4][2048][1024] f32

  char* ws = (char*)d_ws;
  const size_t MB = 1024 * 1024;

  // group size: nb batches per pipeline pass. ws need = 8 + 16*nb MB.
  const int nb = (ws_size >= 72 * MB) ? 4 : (ws_size >= 40 * MB) ? 2 : 1;

  unsigned short* WqT = (unsigned short*)(ws + 0 * MB);              // 2 MB [h][c][d]
  unsigned short* WkT = (unsigned short*)(ws + 2 * MB);              // 2 MB
  unsigned short* WvT = (unsigned short*)(ws + 4 * MB);              // 2 MB
  unsigned short* WoT = (unsigned short*)(ws + 6 * MB);              // 2 MB [n][d]
  unsigned short* QG  = (unsigned short*)(ws + 8 * MB);              // 4*nb MB
  unsigned short* KG  = (unsigned short*)(ws + (8 + 4 * nb) * MB);   // 4*nb MB
  unsigned short* VtG = (unsigned short*)(ws + (8 + 8 * nb) * MB);   // 4*nb MB
  unsigned short* ObG = (unsigned short*)(ws + (8 + 12 * nb) * MB);  // 4*nb MB

  const dim3 tb(32, 8, 1);
  wtrans_kernel<<<dim3(2, 32, 16), tb, 0, stream>>>(Wq, WqT, 1024, 64);
  wtrans_kernel<<<dim3(2, 32, 16), tb, 0, stream>>>(Wk, WkT, 1024, 64);
  wtrans_kernel<<<dim3(2, 32, 16), tb, 0, stream>>>(Wv, WvT, 1024, 64);
  wtrans_kernel<<<dim3(32, 32, 1), tb, 0, stream>>>(Wo, WoT, 1024, 1024);

  for (int g = 0; g < 4; g += nb) {
    const float* embG = emb + (size_t)g * 2048 * 1024;
    float* outG = out + (size_t)g * 2048 * 1024;
    // embB (bf16 emb) aliases ObG: dead before flash writes ObG, per group.
    unsigned short* embB = ObG;
    embconv_kernel<<<dim3(nb * 1024), 256, 0, stream>>>(embG, embB);
    qkv_kernel<<<dim3(8, 16 * nb, 3), 256, 0, stream>>>(embB, WqT, WkT, WvT, QG, KG, VtG);
    flash_kernel<<<dim3(16 * nb, 16), 512, 0, stream>>>(QG, KG, VtG, ObG);
    oproj_kernel<<<dim3(8, 16 * nb), 256, 0, stream>>>(ObG, WoT, bo, outG);
  }
}

// Round 4
// 282.486 us; speedup vs baseline: 1.7497x; 1.0315x over previous
//
#include <hip/hip_runtime.h>
#include <hip/hip_bf16.h>

// B=4, S=2048, D=1024, H=16, DK=DV=64. Inputs f32, output f32 (confirmed r8).
// MFMA math bf16 with f32 accum. Round 13:
//  - qkv/oproj: m97-structure staging via __builtin_amdgcn_global_load_lds
//    (width=16, linear LDS [128][32], wave-uniform dest) -- replaces the
//    reg round-trip (m151: +35% at this exact tile shape).
//  - qkv/oproj: 1D grid + XCD-chunked bijective swizzle, m-major, so all
//    blocks sharing an A-panel run on ONE XCD (L2-resident panel).
//  - flash: unchanged from r12 (balanced pairing, bh-fast grid, setprio).

typedef __attribute__((ext_vector_type(8))) short bf16x8;
typedef __attribute__((ext_vector_type(4))) float f32x4;
typedef __attribute__((ext_vector_type(4))) unsigned int u32x4;
typedef __attribute__((ext_vector_type(2))) unsigned int u32x2;

#define MFMA16(a, b, c) __builtin_amdgcn_mfma_f32_16x16x32_bf16((a), (b), (c), 0, 0, 0)

#define LOG2E 1.44269504088896340736f
#define BIG_NEG (-3.0e38f)
#define DEFER_THR 10.0f  // log2-domain; P bounded by 2^10 when rescale skipped

__device__ __forceinline__ unsigned short f2bf(float f) {
  union { float f; unsigned int i; } x; x.f = f;
  unsigned int lsb = (x.i >> 16) & 1;
  x.i += 0x7fffu + lsb;  // RNE (finite inputs only)
  return (unsigned short)(x.i >> 16);
}

__device__ __forceinline__ unsigned int cvtpk(float lo, float hi) {
  unsigned int r;
  asm("v_cvt_pk_bf16_f32 %0, %1, %2" : "=v"(r) : "v"(lo), "v"(hi));
  return r;
}

// global -> LDS direct DMA, 16B per lane. lds dest must be wave-uniform base;
// HW writes base + lane*16. Global src is per-lane.
__device__ __forceinline__ void gl16(const unsigned short* g, void* l) {
  __builtin_amdgcn_global_load_lds(
      (const __attribute__((address_space(1))) unsigned int*)g,
      (__attribute__((address_space(3))) unsigned int*)l, 16, 0, 0);
}

// ---------------------------------------------------------------------------
// Batched transpose + downconvert: in f32 [batch][R][C] -> out bf16 [batch][C][R]
// ---------------------------------------------------------------------------
__global__ void wtrans_kernel(const float* __restrict__ in,
                              unsigned short* __restrict__ out, int R, int C) {
  __shared__ unsigned short tile[32][33];
  const int bz = blockIdx.z;
  const int c0 = blockIdx.x * 32, r0 = blockIdx.y * 32;
  const float* ip = in + (size_t)bz * R * C;
  unsigned short* op = out + (size_t)bz * R * C;
  const int tx = threadIdx.x, ty = threadIdx.y;  // (32, 8)
#pragma unroll
  for (int i = 0; i < 32; i += 8)
    tile[ty + i][tx] = f2bf(ip[(size_t)(r0 + ty + i) * C + (c0 + tx)]);
  __syncthreads();
#pragma unroll
  for (int i = 0; i < 32; i += 8)
    op[(size_t)(c0 + ty + i) * R + (r0 + tx)] = tile[tx][ty + i];
}

// ---------------------------------------------------------------------------
// f32 -> bf16 bulk convert (emb). Grid covers exactly n/8 threads.
// ---------------------------------------------------------------------------
__global__ __launch_bounds__(256)
void embconv_kernel(const float* __restrict__ in, unsigned short* __restrict__ out) {
  const int i = blockIdx.x * 256 + threadIdx.x;
  const float4 a = ((const float4*)in)[2 * i];
  const float4 b = ((const float4*)in)[2 * i + 1];
  union { unsigned short u[8]; u32x4 v; } p;
  p.u[0] = f2bf(a.x); p.u[1] = f2bf(a.y); p.u[2] = f2bf(a.z); p.u[3] = f2bf(a.w);
  p.u[4] = f2bf(b.x); p.u[5] = f2bf(b.y); p.u[6] = f2bf(b.z); p.u[7] = f2bf(b.w);
  ((u32x4*)out)[i] = p.v;
}

// ---------------------------------------------------------------------------
// QKV projection, GROUP of nb batches: embB bf16 [nb*2048][1024] x WtT bf16
// [h][c][d] -> Q (pre-scaled by 0.125*log2e), K bf16 [(b*16+h)][s][64],
// V transposed -> Vt [(b*16+h)][dv][s].
// 1D grid nwg = 24*MB_CNT, XCD-chunked swizzle, m-major block order.
// Staging: global_load_lds width=16 into linear As/Bs [128][32].
// ---------------------------------------------------------------------------
__global__ __launch_bounds__(256)
void qkv_kernel(const unsigned short* __restrict__ embB,
                const unsigned short* __restrict__ WqT,
                const unsigned short* __restrict__ WkT,
                const unsigned short* __restrict__ WvT,
                unsigned short* __restrict__ QG,
                unsigned short* __restrict__ KG,
                unsigned short* __restrict__ VtG) {
  const int nwg = gridDim.x;                       // 24 * MB_CNT, %8 == 0
  const int wg = blockIdx.x;
  const int swz = (wg & 7) * (nwg >> 3) + (wg >> 3);
  const int mb = swz / 24;                         // embB panel index
  const int rem = swz - mb * 24;
  const int t = rem >> 3;                          // 0=Q, 1=K, 2=V
  const int m0 = mb * 128;
  const int n0 = (rem & 7) * 128;
  const int b = m0 >> 11;                          // local batch
  const int sloc = m0 & 2047;
  const unsigned short* Wt =
      (t == 0 ? WqT : (t == 1 ? WkT : WvT)) + (size_t)(n0 >> 6) * 64 * 1024;

  __shared__ __align__(16) unsigned short As[128 * 32];  // [m][k] linear
  __shared__ __align__(16) unsigned short Bs[128 * 32];  // [n][k] linear

  const int tid = threadIdx.x;
  const int lane = tid & 63, w = tid >> 6;
  const int q4 = lane >> 4, l16 = lane & 15;
  const int lr = lane >> 2, lc = (lane & 3) * 8;   // staging: row/col-in-BK

  f32x4 acc[4][4] = {};

  // wave w stages rows [w*32, w*32+32) of each 128x32 tile (2 x 1KB DMAs)
  const unsigned short* ga0 = &embB[(size_t)(m0 + w * 32 + lr) * 1024 + lc];
  const unsigned short* ga1 = ga0 + 16 * 1024;
  const unsigned short* gb0 = &Wt[(size_t)(w * 32 + lr) * 1024 + lc];
  const unsigned short* gb1 = gb0 + 16 * 1024;
  char* la0 = (char*)As + w * 2048;
  char* lb0 = (char*)Bs + w * 2048;

  for (int k0 = 0; k0 < 1024; k0 += 32) {
    __syncthreads();                 // prev tile's ds_reads complete
    gl16(ga0 + k0, la0);
    gl16(ga1 + k0, la0 + 1024);
    gl16(gb0 + k0, lb0);
    gl16(gb1 + k0, lb0 + 1024);
    __syncthreads();                 // drains vmcnt: tiles visible

    // t==2: compute (W^T * emb^T) = V^T directly by swapping operand roles.
    const unsigned short* PA = (t == 2) ? Bs : As;
    const unsigned short* PB = (t == 2) ? As : Bs;

    bf16x8 af[4], bfr[4];
#pragma unroll
    for (int ms = 0; ms < 4; ++ms)
      af[ms] = *(const bf16x8*)&PA[((w >> 1) * 64 + ms * 16 + l16) * 32 + q4 * 8];
#pragma unroll
    for (int js = 0; js < 4; ++js)
      bfr[js] = *(const bf16x8*)&PB[((w & 1) * 64 + js * 16 + l16) * 32 + q4 * 8];
    __builtin_amdgcn_s_setprio(1);
#pragma unroll
    for (int ms = 0; ms < 4; ++ms)
#pragma unroll
      for (int js = 0; js < 4; ++js)
        acc[ms][js] = MFMA16(af[ms], bfr[js], acc[ms][js]);
    __builtin_amdgcn_s_setprio(0);
  }

  if (t < 2) {
    unsigned short* outp = (t == 0) ? QG : KG;
    const float osc = (t == 0) ? (0.125f * LOG2E) : 1.0f;  // fold softmax scale into Q
    const int h = (n0 >> 6) + (w & 1);
    const size_t hb = (size_t)(b * 16 + h) * 2048;
#pragma unroll
    for (int ms = 0; ms < 4; ++ms)
#pragma unroll
      for (int js = 0; js < 4; ++js) {
        const int c = js * 16 + l16;
#pragma unroll
        for (int r = 0; r < 4; ++r) {
          const int s = sloc + (w >> 1) * 64 + ms * 16 + q4 * 4 + r;
          outp[(hb + s) * 64 + c] = f2bf(acc[ms][js][r] * osc);
        }
      }
  } else {
    const int h = (n0 >> 6) + (w >> 1);
    const size_t hb = (size_t)(b * 16 + h) * 64;
#pragma unroll
    for (int ms = 0; ms < 4; ++ms)
#pragma unroll
      for (int js = 0; js < 4; ++js) {
        const int s = sloc + (w & 1) * 64 + js * 16 + l16;
#pragma unroll
        for (int r = 0; r < 4; ++r) {
          const int c = ms * 16 + q4 * 4 + r;
          VtG[(hb + c) * 2048 + s] = f2bf(acc[ms][js][r]);
        }
      }
  }
}

// ---------------------------------------------------------------------------
// Flash attention, causal, balanced pairing. Grid (16*nb bh, 16 x), 512 thr.
// Block (bh, x) handles q-tiles (31-x) [waves 0-3] and (x) [waves 4-7].
// bh in the FAST grid dim: round-robin dispatch then gives each CU a spread
// of x values (uniform CU busy-time). Swapped-operand S^T = mfma(K,Q).
// ---------------------------------------------------------------------------
__global__ __launch_bounds__(512)
void flash_kernel(const unsigned short* __restrict__ QG,
                  const unsigned short* __restrict__ KG,
                  const unsigned short* __restrict__ VtG,
                  unsigned short* __restrict__ ObG) {
  const int bh = blockIdx.x;
  const int x = blockIdx.y;                 // 0..15
  const int q0B = (31 - x) * 64;            // long phase (waves 0-3)
  const int tid = threadIdx.x;
  const int lane = tid & 63, w = tid >> 6;  // w in 0..7
  const int wp = w & 3;
  const int q0w = (w < 4) ? q0B : x * 64;   // this wave's q-tile base
  const int q4 = lane >> 4, l16 = lane & 15;

  const unsigned short* Qp = QG + ((size_t)bh * 2048 + q0w + wp * 16) * 64;
  const unsigned short* Kp = KG + (size_t)bh * 2048 * 64;
  const unsigned short* Vp = VtG + (size_t)bh * 64 * 2048;

  // B-fragment of Q for S^T mfma: lane holds Q[q=l16][d=q4*8..+8] (pre-scaled)
  const bf16x8 qf0 = *(const bf16x8*)&Qp[(size_t)l16 * 64 + q4 * 8];
  const bf16x8 qf1 = *(const bf16x8*)&Qp[(size_t)l16 * 64 + 32 + q4 * 8];

  __shared__ __align__(16) unsigned short Ks[64][72];       // [s][d]
  __shared__ __align__(16) unsigned short Vs[64][72];       // [dv][s]
  __shared__ __align__(16) unsigned short Plds[8][16][72];  // per-wave P[q][k]

  f32x4 oacc[4] = {};  // O^T: oacc[js][r] = O[q=l16][dv=js*16+q4*4+r]
  float m_i = BIG_NEG, l_i = 0.f;

  // staging: 512 threads, one 16B K-slice + one 16B V-slice each
  const int sr = tid >> 3, sc = (tid & 7) * 8;
  u32x4 kreg = *(const u32x4*)&Kp[(size_t)sr * 64 + sc];
  u32x4 vreg = *(const u32x4*)&Vp[(size_t)sr * 2048 + sc];

  for (int j0 = 0; j0 <= q0B; j0 += 64) {
    *(u32x4*)&Ks[sr][sc] = kreg;
    *(u32x4*)&Vs[sr][sc] = vreg;
    __syncthreads();

    // prefetch next tile into regs; overlaps with the compute below (T14)
    if (j0 + 64 <= q0B) {
      const int jn = j0 + 64;
      kreg = *(const u32x4*)&Kp[(size_t)(jn + sr) * 64 + sc];
      vreg = *(const u32x4*)&Vp[(size_t)sr * 2048 + jn + sc];
    }

    if (j0 <= q0w) {  // wave-uniform: this wave's q-tile still has work
      // S^T tile: sacc[js][r] = S[q=l16][k = js*16 + q4*4 + r] (log2 domain)
      f32x4 sacc[4] = {};
      __builtin_amdgcn_s_setprio(1);
#pragma unroll
      for (int js = 0; js < 4; ++js) {
        const bf16x8 kf0 = *(const bf16x8*)&Ks[js * 16 + l16][q4 * 8];
        const bf16x8 kf1 = *(const bf16x8*)&Ks[js * 16 + l16][32 + q4 * 8];
        sacc[js] = MFMA16(kf0, qf0, sacc[js]);
        sacc[js] = MFMA16(kf1, qf1, sacc[js]);
      }
      __builtin_amdgcn_s_setprio(0);

      // causal mask (diag tile only) + in-lane max
      float mloc = BIG_NEG;
      if (j0 == q0w) {
        const int qrel = wp * 16 + l16;
#pragma unroll
        for (int js = 0; js < 4; ++js)
#pragma unroll
          for (int r = 0; r < 4; ++r) {
            const int krel = js * 16 + q4 * 4 + r;
            float v = sacc[js][r];
            if (krel > qrel) v = BIG_NEG;
            sacc[js][r] = v;
            mloc = fmaxf(mloc, v);
          }
      } else {
#pragma unroll
        for (int js = 0; js < 4; ++js)
#pragma unroll
          for (int r = 0; r < 4; ++r) mloc = fmaxf(mloc, sacc[js][r]);
      }
      // row max across the 4 q4-groups sharing q=l16
      mloc = fmaxf(mloc, __shfl_xor(mloc, 16, 64));
      mloc = fmaxf(mloc, __shfl_xor(mloc, 32, 64));

      // defer-max (T13): only rescale when the running max grew past THR
      if (__any(mloc > m_i + DEFER_THR)) {
        const float mnew = fmaxf(m_i, mloc);
        const float alpha = __builtin_amdgcn_exp2f(m_i - mnew);
        m_i = mnew;
        l_i *= alpha;
#pragma unroll
        for (int js = 0; js < 4; ++js)
#pragma unroll
          for (int r = 0; r < 4; ++r) oacc[js][r] *= alpha;
      }

      float sm = 0.f;
#pragma unroll
      for (int js = 0; js < 4; ++js)
#pragma unroll
        for (int r = 0; r < 4; ++r) {
          const float p = __builtin_amdgcn_exp2f(sacc[js][r] - m_i);
          sacc[js][r] = p;
          sm += p;
        }
      sm += __shfl_xor(sm, 16, 64);
      sm += __shfl_xor(sm, 32, 64);
      l_i += sm;

      // P store: row q=l16, 4 consecutive k per js -> one 8B write each
#pragma unroll
      for (int js = 0; js < 4; ++js) {
        u32x2 pk;
        pk[0] = cvtpk(sacc[js][0], sacc[js][1]);
        pk[1] = cvtpk(sacc[js][2], sacc[js][3]);
        *(u32x2*)&Plds[w][l16][js * 16 + q4 * 4] = pk;
      }

      asm volatile("" ::: "memory");

      // B-fragment of P^T: lane needs P[q=l16][k=q4*8..+8]
      const bf16x8 pf0 = *(const bf16x8*)&Plds[w][l16][q4 * 8];
      const bf16x8 pf1 = *(const bf16x8*)&Plds[w][l16][32 + q4 * 8];

      __builtin_amdgcn_s_setprio(1);
#pragma unroll
      for (int js = 0; js < 4; ++js) {
        const bf16x8 vf0 = *(const bf16x8*)&Vs[js * 16 + l16][q4 * 8];
        const bf16x8 vf1 = *(const bf16x8*)&Vs[js * 16 + l16][32 + q4 * 8];
        oacc[js] = MFMA16(vf0, pf0, oacc[js]);
        oacc[js] = MFMA16(vf1, pf1, oacc[js]);
      }
      __builtin_amdgcn_s_setprio(0);
    }
    __syncthreads();  // all LDS reads done before next iter's staging writes
  }

  // epilogue: concat-head layout ObG[b][s][h*64+dv]; 4 consecutive dv per 8B
  const int b = bh >> 4, h = bh & 15;
  const int q = q0w + wp * 16 + l16;
  const float rl = 1.0f / l_i;
  unsigned short* orow = ObG + ((size_t)b * 2048 + q) * 1024 + h * 64;
#pragma unroll
  for (int js = 0; js < 4; ++js) {
    u32x2 ok;
    ok[0] = cvtpk(oacc[js][0] * rl, oacc[js][1] * rl);
    ok[1] = cvtpk(oacc[js][2] * rl, oacc[js][3] * rl);
    *(u32x2*)&orow[js * 16 + q4 * 4] = ok;
  }
}

// ---------------------------------------------------------------------------
// Output projection, GROUP: ObG bf16 [nb*2048][1024] x WoT bf16 [n][d]
// + bo(f32) -> outG f32 [nb*2048][1024].
// 1D grid nwg = 8*MB_CNT, XCD-chunked swizzle, m-major. gl16 staging.
// ---------------------------------------------------------------------------
__global__ __launch_bounds__(256)
void oproj_kernel(const unsigned short* __restrict__ ObG,
                  const unsigned short* __restrict__ WoT,
                  const float* __restrict__ bo,
                  float* __restrict__ outG) {
  const int nwg = gridDim.x;                       // 8 * MB_CNT, %8 == 0
  const int wg = blockIdx.x;
  const int swz = (wg & 7) * (nwg >> 3) + (wg >> 3);
  const int m0 = (swz >> 3) * 128;
  const int n0 = (swz & 7) * 128;

  __shared__ __align__(16) unsigned short As[128 * 32];
  __shared__ __align__(16) unsigned short Bs[128 * 32];

  const int tid = threadIdx.x;
  const int lane = tid & 63, w = tid >> 6;
  const int q4 = lane >> 4, l16 = lane & 15;
  const int lr = lane >> 2, lc = (lane & 3) * 8;

  f32x4 acc[4][4] = {};

  const unsigned short* ga0 = &ObG[(size_t)(m0 + w * 32 + lr) * 1024 + lc];
  const unsigned short* ga1 = ga0 + 16 * 1024;
  const unsigned short* gb0 = &WoT[(size_t)(n0 + w * 32 + lr) * 1024 + lc];
  const unsigned short* gb1 = gb0 + 16 * 1024;
  char* la0 = (char*)As + w * 2048;
  char* lb0 = (char*)Bs + w * 2048;

  for (int k0 = 0; k0 < 1024; k0 += 32) {
    __syncthreads();
    gl16(ga0 + k0, la0);
    gl16(ga1 + k0, la0 + 1024);
    gl16(gb0 + k0, lb0);
    gl16(gb1 + k0, lb0 + 1024);
    __syncthreads();

    bf16x8 af[4], bfr[4];
#pragma unroll
    for (int ms = 0; ms < 4; ++ms)
      af[ms] = *(const bf16x8*)&As[((w >> 1) * 64 + ms * 16 + l16) * 32 + q4 * 8];
#pragma unroll
    for (int js = 0; js < 4; ++js)
      bfr[js] = *(const bf16x8*)&Bs[((w & 1) * 64 + js * 16 + l16) * 32 + q4 * 8];
    __builtin_amdgcn_s_setprio(1);
#pragma unroll
    for (int ms = 0; ms < 4; ++ms)
#pragma unroll
      for (int js = 0; js < 4; ++js)
        acc[ms][js] = MFMA16(af[ms], bfr[js], acc[ms][js]);
    __builtin_amdgcn_s_setprio(0);
  }

#pragma unroll
  for (int js = 0; js < 4; ++js) {
    const int col = n0 + (w & 1) * 64 + js * 16 + l16;
    const float bias = bo[col];
#pragma unroll
    for (int ms = 0; ms < 4; ++ms)
#pragma unroll
      for (int r = 0; r < 4; ++r) {
        const int row = m0 + (w >> 1) * 64 + ms * 16 + q4 * 4 + r;
        outG[(size_t)row * 1024 + col] = acc[ms][js][r] + bias;  // f32 store
      }
  }
}

// ---------------------------------------------------------------------------
extern "C" void kernel_launch(void* const* d_in, const int* in_sizes, int n_in,
                              void* d_out, int out_size, void* d_ws, size_t ws_size,
                              hipStream_t stream) {
  const float* emb = (const float*)d_in[0];   // [4][2048][1024] f32
  const float* Wq  = (const float*)d_in[1];   // [16][1024][64]  f32
  const float* Wk  = (const float*)d_in[2];
  const float* Wv  = (const float*)d_in[3];
  const float* Wo  = (const float*)d_in[4];   // [1024][1024]    f32
  const float* bo  = (const float*)d_in[5];   // [1024]          f32
  float* out = (float*)d_out;                 // [4][2048][1024] f32

  char* ws = (char*)d_ws;
  const size_t MB = 1024 * 1024;

  // group size: nb batches per pipeline pass. ws need = 8 + 16*nb MB.
  const int nb = (ws_size >= 72 * MB) ? 4 : (ws_size >= 40 * MB) ? 2 : 1;

  unsigned short* WqT = (unsigned short*)(ws + 0 * MB);              // 2 MB [h][c][d]
  unsigned short* WkT = (unsigned short*)(ws + 2 * MB);              // 2 MB
  unsigned short* WvT = (unsigned short*)(ws + 4 * MB);              // 2 MB
  unsigned short* WoT = (unsigned short*)(ws + 6 * MB);              // 2 MB [n][d]
  unsigned short* QG  = (unsigned short*)(ws + 8 * MB);              // 4*nb MB
  unsigned short* KG  = (unsigned short*)(ws + (8 + 4 * nb) * MB);   // 4*nb MB
  unsigned short* VtG = (unsigned short*)(ws + (8 + 8 * nb) * MB);   // 4*nb MB
  unsigned short* ObG = (unsigned short*)(ws + (8 + 12 * nb) * MB);  // 4*nb MB

  const dim3 tb(32, 8, 1);
  wtrans_kernel<<<dim3(2, 32, 16), tb, 0, stream>>>(Wq, WqT, 1024, 64);
  wtrans_kernel<<<dim3(2, 32, 16), tb, 0, stream>>>(Wk, WkT, 1024, 64);
  wtrans_kernel<<<dim3(2, 32, 16), tb, 0, stream>>>(Wv, WvT, 1024, 64);
  wtrans_kernel<<<dim3(32, 32, 1), tb, 0, stream>>>(Wo, WoT, 1024, 1024);

  for (int g = 0; g < 4; g += nb) {
    const float* embG = emb + (size_t)g * 2048 * 1024;
    float* outG = out + (size_t)g * 2048 * 1024;
    // embB (bf16 emb) aliases ObG: dead before flash writes ObG, per group.
    unsigned short* embB = ObG;
    embconv_kernel<<<dim3(nb * 1024), 256, 0, stream>>>(embG, embB);
    qkv_kernel<<<dim3(24 * 16 * nb), 256, 0, stream>>>(embB, WqT, WkT, WvT, QG, KG, VtG);
    flash_kernel<<<dim3(16 * nb, 16), 512, 0, stream>>>(QG, KG, VtG, ObG);
    oproj_kernel<<<dim3(8 * 16 * nb), 256, 0, stream>>>(ObG, WoT, bo, outG);
  }
}

// Round 6
// 280.446 us; speedup vs baseline: 1.7625x; 1.0073x over previous
//
#include <hip/hip_runtime.h>
#include <hip/hip_bf16.h>

// B=4, S=2048, D=1024, H=16, DK=DV=64. Inputs f32, output f32 (confirmed r8).
// MFMA math bf16 with f32 accum. Round 15 (= r14 resubmit; infra failure):
//  - flash: 128-row q-tile per block (8 waves ALL active: 97% wave-slot
//    efficiency vs 67% for r11 pairing; 1.44x fewer stagings/barriers).
//    CU-balancing y->t swizzle: every CU's 4 resident blocks sum to the
//    same iteration count (68). Deferred l-sum reduce (epilogue only).
//  - qkv/oproj: unchanged from r13 (gl16 staging + XCD-chunked swizzle).

typedef __attribute__((ext_vector_type(8))) short bf16x8;
typedef __attribute__((ext_vector_type(4))) float f32x4;
typedef __attribute__((ext_vector_type(4))) unsigned int u32x4;
typedef __attribute__((ext_vector_type(2))) unsigned int u32x2;

#define MFMA16(a, b, c) __builtin_amdgcn_mfma_f32_16x16x32_bf16((a), (b), (c), 0, 0, 0)

#define LOG2E 1.44269504088896340736f
#define BIG_NEG (-3.0e38f)
#define DEFER_THR 10.0f  // log2-domain; P bounded by 2^10 when rescale skipped

__device__ __forceinline__ unsigned short f2bf(float f) {
  union { float f; unsigned int i; } x; x.f = f;
  unsigned int lsb = (x.i >> 16) & 1;
  x.i += 0x7fffu + lsb;  // RNE (finite inputs only)
  return (unsigned short)(x.i >> 16);
}

__device__ __forceinline__ unsigned int cvtpk(float lo, float hi) {
  unsigned int r;
  asm("v_cvt_pk_bf16_f32 %0, %1, %2" : "=v"(r) : "v"(lo), "v"(hi));
  return r;
}

// global -> LDS direct DMA, 16B per lane. lds dest must be wave-uniform base;
// HW writes base + lane*16. Global src is per-lane.
__device__ __forceinline__ void gl16(const unsigned short* g, void* l) {
  __builtin_amdgcn_global_load_lds(
      (const __attribute__((address_space(1))) unsigned int*)g,
      (__attribute__((address_space(3))) unsigned int*)l, 16, 0, 0);
}

// ---------------------------------------------------------------------------
// Batched transpose + downconvert: in f32 [batch][R][C] -> out bf16 [batch][C][R]
// ---------------------------------------------------------------------------
__global__ void wtrans_kernel(const float* __restrict__ in,
                              unsigned short* __restrict__ out, int R, int C) {
  __shared__ unsigned short tile[32][33];
  const int bz = blockIdx.z;
  const int c0 = blockIdx.x * 32, r0 = blockIdx.y * 32;
  const float* ip = in + (size_t)bz * R * C;
  unsigned short* op = out + (size_t)bz * R * C;
  const int tx = threadIdx.x, ty = threadIdx.y;  // (32, 8)
#pragma unroll
  for (int i = 0; i < 32; i += 8)
    tile[ty + i][tx] = f2bf(ip[(size_t)(r0 + ty + i) * C + (c0 + tx)]);
  __syncthreads();
#pragma unroll
  for (int i = 0; i < 32; i += 8)
    op[(size_t)(c0 + ty + i) * R + (r0 + tx)] = tile[tx][ty + i];
}

// ---------------------------------------------------------------------------
// f32 -> bf16 bulk convert (emb). Grid covers exactly n/8 threads.
// ---------------------------------------------------------------------------
__global__ __launch_bounds__(256)
void embconv_kernel(const float* __restrict__ in, unsigned short* __restrict__ out) {
  const int i = blockIdx.x * 256 + threadIdx.x;
  const float4 a = ((const float4*)in)[2 * i];
  const float4 b = ((const float4*)in)[2 * i + 1];
  union { unsigned short u[8]; u32x4 v; } p;
  p.u[0] = f2bf(a.x); p.u[1] = f2bf(a.y); p.u[2] = f2bf(a.z); p.u[3] = f2bf(a.w);
  p.u[4] = f2bf(b.x); p.u[5] = f2bf(b.y); p.u[6] = f2bf(b.z); p.u[7] = f2bf(b.w);
  ((u32x4*)out)[i] = p.v;
}

// ---------------------------------------------------------------------------
// QKV projection, GROUP of nb batches: embB bf16 [nb*2048][1024] x WtT bf16
// [h][c][d] -> Q (pre-scaled by 0.125*log2e), K bf16 [(b*16+h)][s][64],
// V transposed -> Vt [(b*16+h)][dv][s].
// 1D grid nwg = 24*MB_CNT, XCD-chunked swizzle, m-major block order.
// Staging: global_load_lds width=16 into linear As/Bs [128][32].
// ---------------------------------------------------------------------------
__global__ __launch_bounds__(256)
void qkv_kernel(const unsigned short* __restrict__ embB,
                const unsigned short* __restrict__ WqT,
                const unsigned short* __restrict__ WkT,
                const unsigned short* __restrict__ WvT,
                unsigned short* __restrict__ QG,
                unsigned short* __restrict__ KG,
                unsigned short* __restrict__ VtG) {
  const int nwg = gridDim.x;                       // 24 * MB_CNT, %8 == 0
  const int wg = blockIdx.x;
  const int swz = (wg & 7) * (nwg >> 3) + (wg >> 3);
  const int mb = swz / 24;                         // embB panel index
  const int rem = swz - mb * 24;
  const int t = rem >> 3;                          // 0=Q, 1=K, 2=V
  const int m0 = mb * 128;
  const int n0 = (rem & 7) * 128;
  const int b = m0 >> 11;                          // local batch
  const int sloc = m0 & 2047;
  const unsigned short* Wt =
      (t == 0 ? WqT : (t == 1 ? WkT : WvT)) + (size_t)(n0 >> 6) * 64 * 1024;

  __shared__ __align__(16) unsigned short As[128 * 32];  // [m][k] linear
  __shared__ __align__(16) unsigned short Bs[128 * 32];  // [n][k] linear

  const int tid = threadIdx.x;
  const int lane = tid & 63, w = tid >> 6;
  const int q4 = lane >> 4, l16 = lane & 15;
  const int lr = lane >> 2, lc = (lane & 3) * 8;   // staging: row/col-in-BK

  f32x4 acc[4][4] = {};

  // wave w stages rows [w*32, w*32+32) of each 128x32 tile (2 x 1KB DMAs)
  const unsigned short* ga0 = &embB[(size_t)(m0 + w * 32 + lr) * 1024 + lc];
  const unsigned short* ga1 = ga0 + 16 * 1024;
  const unsigned short* gb0 = &Wt[(size_t)(w * 32 + lr) * 1024 + lc];
  const unsigned short* gb1 = gb0 + 16 * 1024;
  char* la0 = (char*)As + w * 2048;
  char* lb0 = (char*)Bs + w * 2048;

  for (int k0 = 0; k0 < 1024; k0 += 32) {
    __syncthreads();                 // prev tile's ds_reads complete
    gl16(ga0 + k0, la0);
    gl16(ga1 + k0, la0 + 1024);
    gl16(gb0 + k0, lb0);
    gl16(gb1 + k0, lb0 + 1024);
    __syncthreads();                 // drains vmcnt: tiles visible

    // t==2: compute (W^T * emb^T) = V^T directly by swapping operand roles.
    const unsigned short* PA = (t == 2) ? Bs : As;
    const unsigned short* PB = (t == 2) ? As : Bs;

    bf16x8 af[4], bfr[4];
#pragma unroll
    for (int ms = 0; ms < 4; ++ms)
      af[ms] = *(const bf16x8*)&PA[((w >> 1) * 64 + ms * 16 + l16) * 32 + q4 * 8];
#pragma unroll
    for (int js = 0; js < 4; ++js)
      bfr[js] = *(const bf16x8*)&PB[((w & 1) * 64 + js * 16 + l16) * 32 + q4 * 8];
    __builtin_amdgcn_s_setprio(1);
#pragma unroll
    for (int ms = 0; ms < 4; ++ms)
#pragma unroll
      for (int js = 0; js < 4; ++js)
        acc[ms][js] = MFMA16(af[ms], bfr[js], acc[ms][js]);
    __builtin_amdgcn_s_setprio(0);
  }

  if (t < 2) {
    unsigned short* outp = (t == 0) ? QG : KG;
    const float osc = (t == 0) ? (0.125f * LOG2E) : 1.0f;  // fold softmax scale into Q
    const int h = (n0 >> 6) + (w & 1);
    const size_t hb = (size_t)(b * 16 + h) * 2048;
#pragma unroll
    for (int ms = 0; ms < 4; ++ms)
#pragma unroll
      for (int js = 0; js < 4; ++js) {
        const int c = js * 16 + l16;
#pragma unroll
        for (int r = 0; r < 4; ++r) {
          const int s = sloc + (w >> 1) * 64 + ms * 16 + q4 * 4 + r;
          outp[(hb + s) * 64 + c] = f2bf(acc[ms][js][r] * osc);
        }
      }
  } else {
    const int h = (n0 >> 6) + (w >> 1);
    const size_t hb = (size_t)(b * 16 + h) * 64;
#pragma unroll
    for (int ms = 0; ms < 4; ++ms)
#pragma unroll
      for (int js = 0; js < 4; ++js) {
        const int s = sloc + (w & 1) * 64 + js * 16 + l16;
#pragma unroll
        for (int r = 0; r < 4; ++r) {
          const int c = ms * 16 + q4 * 4 + r;
          VtG[(hb + c) * 2048 + s] = f2bf(acc[ms][js][r]);
        }
      }
  }
}

// ---------------------------------------------------------------------------
// Flash attention, causal. Grid (16*nb bh, 16 y), 512 thr (8 waves).
// Block owns ONE 128-row q-tile t (y->t CU-balancing swizzle); wave w owns
// rows q0+16w..+15. All 8 waves active every iteration (97% slot efficiency).
// Iterations per block = 2t+2; each CU's 4 resident blocks sum to 68 iters.
// Swapped-operand S^T = mfma(K,Q): softmax row is lane-local (q=l16).
// Deferred l-sum: per-lane partial, reduced once in epilogue.
// ---------------------------------------------------------------------------
__global__ __launch_bounds__(512)
void flash_kernel(const unsigned short* __restrict__ QG,
                  const unsigned short* __restrict__ KG,
                  const unsigned short* __restrict__ VtG,
                  unsigned short* __restrict__ ObG) {
  const int bh = blockIdx.x;
  const int y = blockIdx.y;                 // 0..15
  const int k4 = y >> 2, y0 = y & 3;
  const int t = k4 + 4 * ((y0 + k4) & 3);   // CU-balancing bijective swizzle
  const int q0 = t * 128;
  const int tid = threadIdx.x;
  const int lane = tid & 63, w = tid >> 6;  // w in 0..7
  const int wp = w & 3;
  const int q4 = lane >> 4, l16 = lane & 15;
  const int qw = q0 + w * 16;               // wave's first q-row
  const int jlim = q0 + ((w >= 4) ? 64 : 0);  // last j-tile this wave computes
  const int jlimB = q0 + 64;                  // block's last j-tile

  const unsigned short* Qp = QG + ((size_t)bh * 2048 + qw) * 64;
  const unsigned short* Kp = KG + (size_t)bh * 2048 * 64;
  const unsigned short* Vp = VtG + (size_t)bh * 64 * 2048;

  // B-fragment of Q for S^T mfma: lane holds Q[q=l16][d=q4*8..+8] (pre-scaled)
  const bf16x8 qf0 = *(const bf16x8*)&Qp[(size_t)l16 * 64 + q4 * 8];
  const bf16x8 qf1 = *(const bf16x8*)&Qp[(size_t)l16 * 64 + 32 + q4 * 8];

  __shared__ __align__(16) unsigned short Ks[64][72];       // [s][d]
  __shared__ __align__(16) unsigned short Vs[64][72];       // [dv][s]
  __shared__ __align__(16) unsigned short Plds[8][16][72];  // per-wave P[q][k]

  f32x4 oacc[4] = {};  // O^T: oacc[js][r] = O[q=l16][dv=js*16+q4*4+r]
  float m_i = BIG_NEG, l_part = 0.f;  // l_part: this lane's 16-col partial

  // staging: 512 threads, one 16B K-slice + one 16B V-slice each
  const int sr = tid >> 3, sc = (tid & 7) * 8;
  u32x4 kreg = *(const u32x4*)&Kp[(size_t)sr * 64 + sc];
  u32x4 vreg = *(const u32x4*)&Vp[(size_t)sr * 2048 + sc];

  for (int j0 = 0; j0 <= jlimB; j0 += 64) {
    *(u32x4*)&Ks[sr][sc] = kreg;
    *(u32x4*)&Vs[sr][sc] = vreg;
    __syncthreads();

    // prefetch next tile into regs; overlaps with the compute below (T14)
    if (j0 + 64 <= jlimB) {
      const int jn = j0 + 64;
      kreg = *(const u32x4*)&Kp[(size_t)(jn + sr) * 64 + sc];
      vreg = *(const u32x4*)&Vp[(size_t)sr * 2048 + jn + sc];
    }

    if (j0 <= jlim) {  // wave-uniform: this wave still has causal work
      // S^T tile: sacc[js][r] = S[q=l16][k = js*16 + q4*4 + r] (log2 domain)
      f32x4 sacc[4] = {};
      __builtin_amdgcn_s_setprio(1);
#pragma unroll
      for (int js = 0; js < 4; ++js) {
        const bf16x8 kf0 = *(const bf16x8*)&Ks[js * 16 + l16][q4 * 8];
        const bf16x8 kf1 = *(const bf16x8*)&Ks[js * 16 + l16][32 + q4 * 8];
        sacc[js] = MFMA16(kf0, qf0, sacc[js]);
        sacc[js] = MFMA16(kf1, qf1, sacc[js]);
      }
      __builtin_amdgcn_s_setprio(0);

      // causal mask (edge tile only) + in-lane max
      float mloc = BIG_NEG;
      if (j0 == jlim) {
        const int qrel = wp * 16 + l16;  // wave's row offset within this j-tile
#pragma unroll
        for (int js = 0; js < 4; ++js)
#pragma unroll
          for (int r = 0; r < 4; ++r) {
            const int krel = js * 16 + q4 * 4 + r;
            float v = sacc[js][r];
            if (krel > qrel) v = BIG_NEG;
            sacc[js][r] = v;
            mloc = fmaxf(mloc, v);
          }
      } else {
#pragma unroll
        for (int js = 0; js < 4; ++js)
#pragma unroll
          for (int r = 0; r < 4; ++r) mloc = fmaxf(mloc, sacc[js][r]);
      }
      // row max across the 4 q4-groups sharing q=l16
      mloc = fmaxf(mloc, __shfl_xor(mloc, 16, 64));
      mloc = fmaxf(mloc, __shfl_xor(mloc, 32, 64));

      // defer-max (T13): only rescale when the running max grew past THR
      if (__any(mloc > m_i + DEFER_THR)) {
        const float mnew = fmaxf(m_i, mloc);
        const float alpha = __builtin_amdgcn_exp2f(m_i - mnew);
        m_i = mnew;
        l_part *= alpha;
#pragma unroll
        for (int js = 0; js < 4; ++js)
#pragma unroll
          for (int r = 0; r < 4; ++r) oacc[js][r] *= alpha;
      }

#pragma unroll
      for (int js = 0; js < 4; ++js)
#pragma unroll
        for (int r = 0; r < 4; ++r) {
          const float p = __builtin_amdgcn_exp2f(sacc[js][r] - m_i);
          sacc[js][r] = p;
          l_part += p;  // sum reduce deferred to epilogue
        }

      // P store: row q=l16, 4 consecutive k per js -> one 8B write each
#pragma unroll
      for (int js = 0; js < 4; ++js) {
        u32x2 pk;
        pk[0] = cvtpk(sacc[js][0], sacc[js][1]);
        pk[1] = cvtpk(sacc[js][2], sacc[js][3]);
        *(u32x2*)&Plds[w][l16][js * 16 + q4 * 4] = pk;
      }

      asm volatile("" ::: "memory");

      // B-fragment of P^T: lane needs P[q=l16][k=q4*8..+8]
      const bf16x8 pf0 = *(const bf16x8*)&Plds[w][l16][q4 * 8];
      const bf16x8 pf1 = *(const bf16x8*)&Plds[w][l16][32 + q4 * 8];

      __builtin_amdgcn_s_setprio(1);
#pragma unroll
      for (int js = 0; js < 4; ++js) {
        const bf16x8 vf0 = *(const bf16x8*)&Vs[js * 16 + l16][q4 * 8];
        const bf16x8 vf1 = *(const bf16x8*)&Vs[js * 16 + l16][32 + q4 * 8];
        oacc[js] = MFMA16(vf0, pf0, oacc[js]);
        oacc[js] = MFMA16(vf1, pf1, oacc[js]);
      }
      __builtin_amdgcn_s_setprio(0);
    }
    __syncthreads();  // all LDS reads done before next iter's staging writes
  }

  // epilogue: reduce deferred l across the 4 q4-groups, then write O.
  float l_i = l_part;
  l_i += __shfl_xor(l_i, 16, 64);
  l_i += __shfl_xor(l_i, 32, 64);

  // concat-head layout ObG[b][s][h*64+dv]; 4 consecutive dv per 8B store
  const int b = bh >> 4, h = bh & 15;
  const int q = qw + l16;
  const float rl = 1.0f / l_i;
  unsigned short* orow = ObG + ((size_t)b * 2048 + q) * 1024 + h * 64;
#pragma unroll
  for (int js = 0; js < 4; ++js) {
    u32x2 ok;
    ok[0] = cvtpk(oacc[js][0] * rl, oacc[js][1] * rl);
    ok[1] = cvtpk(oacc[js][2] * rl, oacc[js][3] * rl);
    *(u32x2*)&orow[js * 16 + q4 * 4] = ok;
  }
}

// ---------------------------------------------------------------------------
// Output projection, GROUP: ObG bf16 [nb*2048][1024] x WoT bf16 [n][d]
// + bo(f32) -> outG f32 [nb*2048][1024].
// 1D grid nwg = 8*MB_CNT, XCD-chunked swizzle, m-major. gl16 staging.
// ---------------------------------------------------------------------------
__global__ __launch_bounds__(256)
void oproj_kernel(const unsigned short* __restrict__ ObG,
                  const unsigned short* __restrict__ WoT,
                  const float* __restrict__ bo,
                  float* __restrict__ outG) {
  const int nwg = gridDim.x;                       // 8 * MB_CNT, %8 == 0
  const int wg = blockIdx.x;
  const int swz = (wg & 7) * (nwg >> 3) + (wg >> 3);
  const int m0 = (swz >> 3) * 128;
  const int n0 = (swz & 7) * 128;

  __shared__ __align__(16) unsigned short As[128 * 32];
  __shared__ __align__(16) unsigned short Bs[128 * 32];

  const int tid = threadIdx.x;
  const int lane = tid & 63, w = tid >> 6;
  const int q4 = lane >> 4, l16 = lane & 15;
  const int lr = lane >> 2, lc = (lane & 3) * 8;

  f32x4 acc[4][4] = {};

  const unsigned short* ga0 = &ObG[(size_t)(m0 + w * 32 + lr) * 1024 + lc];
  const unsigned short* ga1 = ga0 + 16 * 1024;
  const unsigned short* gb0 = &WoT[(size_t)(n0 + w * 32 + lr) * 1024 + lc];
  const unsigned short* gb1 = gb0 + 16 * 1024;
  char* la0 = (char*)As + w * 2048;
  char* lb0 = (char*)Bs + w * 2048;

  for (int k0 = 0; k0 < 1024; k0 += 32) {
    __syncthreads();
    gl16(ga0 + k0, la0);
    gl16(ga1 + k0, la0 + 1024);
    gl16(gb0 + k0, lb0);
    gl16(gb1 + k0, lb0 + 1024);
    __syncthreads();

    bf16x8 af[4], bfr[4];
#pragma unroll
    for (int ms = 0; ms < 4; ++ms)
      af[ms] = *(const bf16x8*)&As[((w >> 1) * 64 + ms * 16 + l16) * 32 + q4 * 8];
#pragma unroll
    for (int js = 0; js < 4; ++js)
      bfr[js] = *(const bf16x8*)&Bs[((w & 1) * 64 + js * 16 + l16) * 32 + q4 * 8];
    __builtin_amdgcn_s_setprio(1);
#pragma unroll
    for (int ms = 0; ms < 4; ++ms)
#pragma unroll
      for (int js = 0; js < 4; ++js)
        acc[ms][js] = MFMA16(af[ms], bfr[js], acc[ms][js]);
    __builtin_amdgcn_s_setprio(0);
  }

#pragma unroll
  for (int js = 0; js < 4; ++js) {
    const int col = n0 + (w & 1) * 64 + js * 16 + l16;
    const float bias = bo[col];
#pragma unroll
    for (int ms = 0; ms < 4; ++ms)
#pragma unroll
      for (int r = 0; r < 4; ++r) {
        const int row = m0 + (w >> 1) * 64 + ms * 16 + q4 * 4 + r;
        outG[(size_t)row * 1024 + col] = acc[ms][js][r] + bias;  // f32 store
      }
  }
}

// ---------------------------------------------------------------------------
extern "C" void kernel_launch(void* const* d_in, const int* in_sizes, int n_in,
                              void* d_out, int out_size, void* d_ws, size_t ws_size,
                              hipStream_t stream) {
  const float* emb = (const float*)d_in[0];   // [4][2048][1024] f32
  const float* Wq  = (const float*)d_in[1];   // [16][1024][64]  f32
  const float* Wk  = (const float*)d_in[2];
  const float* Wv  = (const float*)d_in[3];
  const float* Wo  = (const float*)d_in[4];   // [1024][1024]    f32
  const float* bo  = (const float*)d_in[5];   // [1024]          f32
  float* out = (float*)d_out;                 // [4][2048][1024] f32

  char* ws = (char*)d_ws;
  const size_t MB = 1024 * 1024;

  // group size: nb batches per pipeline pass. ws need = 8 + 16*nb MB.
  const int nb = (ws_size >= 72 * MB) ? 4 : (ws_size >= 40 * MB) ? 2 : 1;

  unsigned short* WqT = (unsigned short*)(ws + 0 * MB);              // 2 MB [h][c][d]
  unsigned short* WkT = (unsigned short*)(ws + 2 * MB);              // 2 MB
  unsigned short* WvT = (unsigned short*)(ws + 4 * MB);              // 2 MB
  unsigned short* WoT = (unsigned short*)(ws + 6 * MB);              // 2 MB [n][d]
  unsigned short* QG  = (unsigned short*)(ws + 8 * MB);              // 4*nb MB
  unsigned short* KG  = (unsigned short*)(ws + (8 + 4 * nb) * MB);   // 4*nb MB
  unsigned short* VtG = (unsigned short*)(ws + (8 + 8 * nb) * MB);   // 4*nb MB
  unsigned short* ObG = (unsigned short*)(ws + (8 + 12 * nb) * MB);  // 4*nb MB

  const dim3 tb(32, 8, 1);
  wtrans_kernel<<<dim3(2, 32, 16), tb, 0, stream>>>(Wq, WqT, 1024, 64);
  wtrans_kernel<<<dim3(2, 32, 16), tb, 0, stream>>>(Wk, WkT, 1024, 64);
  wtrans_kernel<<<dim3(2, 32, 16), tb, 0, stream>>>(Wv, WvT, 1024, 64);
  wtrans_kernel<<<dim3(32, 32, 1), tb, 0, stream>>>(Wo, WoT, 1024, 1024);

  for (int g = 0; g < 4; g += nb) {
    const float* embG = emb + (size_t)g * 2048 * 1024;
    float* outG = out + (size_t)g * 2048 * 1024;
    // embB (bf16 emb) aliases ObG: dead before flash writes ObG, per group.
    unsigned short* embB = ObG;
    embconv_kernel<<<dim3(nb * 1024), 256, 0, stream>>>(embG, embB);
    qkv_kernel<<<dim3(24 * 16 * nb), 256, 0, stream>>>(embB, WqT, WkT, WvT, QG, KG, VtG);
    flash_kernel<<<dim3(16 * nb, 16), 512, 0, stream>>>(QG, KG, VtG, ObG);
    oproj_kernel<<<dim3(8 * 16 * nb), 256, 0, stream>>>(ObG, WoT, bo, outG);
  }
}